// Round 6
// baseline (795.653 us; speedup 1.0000x reference)
//
#include <hip/hip_runtime.h>
#include <math.h>

#define NN   50000
#define NE   1600000
#define DHID 128
#define DOUTC 64
#define NLBL 200000
#define CAP  80          // max in-degree+1; Poisson(32): P(deg>=80) ~ 1e-12/node
#define NEG  0.2f
#define NBK  196         // ceil(50000/256) dst buckets of 256 nodes
#define CAPB 8800        // bucket capacity: Poisson(8163) + 7 sigma
#define CHK  4096        // edges per k_bin block
#define NPASS 49         // src tiles of 1024 for row-sorted insertion

typedef unsigned short u16;

// ---------------- CSR build: binned counting sort, rows src-sorted ----------------

__global__ __launch_bounds__(256) void k_zero(int* __restrict__ gcnt) {
    int i = threadIdx.x;
    if (i < NBK) gcnt[i] = 0;
}

__global__ __launch_bounds__(256) void k_bin(const int* __restrict__ ei,
                                             int* __restrict__ gcnt,
                                             unsigned* __restrict__ bins) {
    __shared__ int cntL[NBK];
    __shared__ int curL[NBK];
    const int tid = threadIdx.x;
    const int e0 = blockIdx.x * CHK + tid * 16;
    const bool act = (e0 + 15) < NE;

    unsigned pk[16];
    int bb[16];
    if (act) {
#pragma unroll
        for (int g = 0; g < 4; ++g) {
            int4 s4 = *(const int4*)&ei[e0 + g * 4];
            int4 d4 = *(const int4*)&ei[NE + e0 + g * 4];
            int sa[4] = {s4.x, s4.y, s4.z, s4.w};
            int da[4] = {d4.x, d4.y, d4.z, d4.w};
#pragma unroll
            for (int k = 0; k < 4; ++k) {
                int idx = g * 4 + k;
                bb[idx] = da[k] >> 8;
                pk[idx] = (unsigned)sa[k] | ((unsigned)(da[k] & 255) << 16);
            }
        }
    }
    for (int i = tid; i < NBK; i += 256) cntL[i] = 0;
    __syncthreads();
    if (act) {
#pragma unroll
        for (int k = 0; k < 16; ++k) atomicAdd(&cntL[bb[k]], 1);
    }
    __syncthreads();
    for (int i = tid; i < NBK; i += 256) curL[i] = atomicAdd(&gcnt[i], cntL[i]);
    __syncthreads();
    if (act) {
#pragma unroll
        for (int k = 0; k < 16; ++k) {
            int off = atomicAdd(&curL[bb[k]], 1);
            bins[(size_t)bb[k] * CAPB + off] = pk[k];
        }
    }
}

// one block per bucket: stage edges in LDS, insert by ascending src tile -> rows ~sorted by src
__global__ __launch_bounds__(256) void k_build(const unsigned* __restrict__ bins,
                                               const int* __restrict__ gcnt,
                                               int* __restrict__ cnt,
                                               u16* __restrict__ csr) {
    __shared__ u16 rows[256 * CAP];      // 40 KB
    __shared__ int cur[256];
    __shared__ unsigned edgesL[CAPB];    // 35.2 KB
    const int b = blockIdx.x, tid = threadIdx.x;
    const int d0 = b << 8;
    const int nd = min(256, NN - d0);
    if (tid < nd) { cur[tid] = 1; rows[tid * CAP] = (u16)(d0 + tid); }  // self-loop slot 0
    int n = gcnt[b]; if (n > CAPB) n = CAPB;
    for (int i = tid; i < n; i += 256) edgesL[i] = bins[(size_t)b * CAPB + i];
    __syncthreads();
    // 49 passes over src tiles (src>>10 ascending); loose thread skew -> minor
    // inversions only, order within a row is irrelevant for correctness.
    for (int t = 0; t < NPASS; ++t) {
        for (int i = tid; i < n; i += 256) {
            unsigned v = edgesL[i];
            int s = v & 0xFFFF;
            if ((s >> 10) == t) {
                int dl = v >> 16;
                int pos = atomicAdd(&cur[dl], 1);
                if (pos < CAP) rows[dl * CAP + pos] = (u16)s;
            }
        }
    }
    __syncthreads();
    const unsigned* rw = (const unsigned*)rows;
    unsigned* cw = (unsigned*)(csr + (size_t)d0 * CAP);
    const int tot = nd * (CAP / 2);
    for (int i = tid; i < tot; i += 256) cw[i] = rw[i];
    if (tid < nd) cnt[d0 + tid] = cur[tid];
}

// ---------------- fp32 GEMM + fused attn dots ----------------

template <int NOUT, bool ATTN>
__global__ __launch_bounds__(256) void gemm_k(const float* __restrict__ A,
                                              const float* __restrict__ W,
                                              float* __restrict__ C,
                                              const float* __restrict__ a_s,
                                              const float* __restrict__ a_d,
                                              float* __restrict__ asv,
                                              float* __restrict__ adv, int M) {
    constexpr int BM = 64, BK = 32, TM = 4, TN = NOUT / 16;
    __shared__ float As[BM][36];
    __shared__ float Ws[BK][NOUT];
    const int tid = threadIdx.x;
    const int tx = tid & 15, ty = tid >> 4;
    const int row0 = blockIdx.x * BM;

    float acc[TM][TN];
#pragma unroll
    for (int i = 0; i < TM; ++i)
#pragma unroll
        for (int j = 0; j < TN; ++j) acc[i][j] = 0.f;

    for (int k0 = 0; k0 < 128; k0 += BK) {
        {
            int r = tid >> 3;
            int c = (tid & 7) * 4;
#pragma unroll
            for (int rr = 0; rr < BM; rr += 32) {
                int grow = row0 + r + rr;
                float4 v = make_float4(0.f, 0.f, 0.f, 0.f);
                if (grow < M) v = *(const float4*)&A[(size_t)grow * 128 + k0 + c];
                *(float4*)&As[r + rr][c] = v;
            }
        }
        {
            constexpr int TOT4 = BK * NOUT / 4;
#pragma unroll
            for (int i4 = tid; i4 < TOT4; i4 += 256) {
                int kk = (i4 * 4) / NOUT;
                int cc = (i4 * 4) % NOUT;
                *(float4*)&Ws[kk][cc] = *(const float4*)&W[(size_t)(k0 + kk) * NOUT + cc];
            }
        }
        __syncthreads();
#pragma unroll
        for (int k4 = 0; k4 < BK; k4 += 4) {
            float a4[TM][4];
#pragma unroll
            for (int i = 0; i < TM; ++i) {
                float4 v = *(const float4*)&As[ty * TM + i][k4];
                a4[i][0] = v.x; a4[i][1] = v.y; a4[i][2] = v.z; a4[i][3] = v.w;
            }
#pragma unroll
            for (int kk = 0; kk < 4; ++kk) {
                int k = k4 + kk;
                float rw[TN];
                if (NOUT == 128) {
                    float4 w0 = *(const float4*)&Ws[k][tx * 4];
                    float4 w1 = *(const float4*)&Ws[k][64 + tx * 4];
                    rw[0] = w0.x; rw[1] = w0.y; rw[2] = w0.z; rw[3] = w0.w;
                    rw[4] = w1.x; rw[5] = w1.y; rw[6] = w1.z; rw[7] = w1.w;
                } else {
                    float4 w0 = *(const float4*)&Ws[k][tx * 4];
                    rw[0] = w0.x; rw[1] = w0.y; rw[2] = w0.z; rw[3] = w0.w;
                }
#pragma unroll
                for (int i = 0; i < TM; ++i)
#pragma unroll
                    for (int j = 0; j < TN; ++j) acc[i][j] = fmaf(a4[i][kk], rw[j], acc[i][j]);
            }
        }
        __syncthreads();
    }
#pragma unroll
    for (int i = 0; i < TM; ++i) {
        int grow = row0 + ty * TM + i;
        if (grow < M) {
            *(float4*)&C[(size_t)grow * NOUT + tx * 4] =
                make_float4(acc[i][0], acc[i][1], acc[i][2], acc[i][3]);
            if (NOUT == 128)
                *(float4*)&C[(size_t)grow * NOUT + 64 + tx * 4] =
                    make_float4(acc[i][4], acc[i][5], acc[i][6], acc[i][7]);
        }
    }
    if (ATTN) {
        float4 s0 = *(const float4*)&a_s[tx * 4];
        float4 s1 = *(const float4*)&a_s[64 + tx * 4];
        float4 d0 = *(const float4*)&a_d[tx * 4];
        float4 d1 = *(const float4*)&a_d[64 + tx * 4];
#pragma unroll
        for (int i = 0; i < TM; ++i) {
            float ps = acc[i][0] * s0.x + acc[i][1] * s0.y + acc[i][2] * s0.z + acc[i][3] * s0.w
                     + acc[i][4] * s1.x + acc[i][5] * s1.y + acc[i][6] * s1.z + acc[i][7] * s1.w;
            float pd = acc[i][0] * d0.x + acc[i][1] * d0.y + acc[i][2] * d0.z + acc[i][3] * d0.w
                     + acc[i][4] * d1.x + acc[i][5] * d1.y + acc[i][6] * d1.z + acc[i][7] * d1.w;
#pragma unroll
            for (int off = 1; off < 16; off <<= 1) {
                ps += __shfl_xor(ps, off);
                pd += __shfl_xor(pd, off);
            }
            int grow = row0 + ty * TM + i;
            if (tx == 0 && grow < M) { asv[grow] = ps; adv[grow] = pd; }
        }
    }
}

// ---------------- GAT aggregation: 8 edge-slots x 8 lanes, branchless ----------------

__global__ __launch_bounds__(256) void k_gat_agg(const float* __restrict__ h,
                                                 const int* __restrict__ cnt,
                                                 const u16* __restrict__ csr,
                                                 const float* __restrict__ asv,
                                                 const float* __restrict__ adv,
                                                 const float* __restrict__ bias,
                                                 float* __restrict__ outp) {
    int lane = threadIdx.x & 63, wv = threadIdx.x >> 6;
    int d = blockIdx.x * 4 + wv;
    if (d >= NN) return;
    int deg = cnt[d]; if (deg > CAP) deg = CAP;
    const float advd = adv[d];
    const u16* rowp = csr + (size_t)d * CAP;

    int j0 = lane, j1 = lane + 64;
    int s0 = 0, s1 = 0;
    float e0 = -INFINITY, e1 = -INFINITY;
    if (j0 < deg) {
        s0 = rowp[j0];
        float t = asv[s0] + advd;
        e0 = (t >= 0.f) ? t : NEG * t;
    }
    if (j1 < deg) {
        s1 = rowp[j1];
        float t = asv[s1] + advd;
        e1 = (t >= 0.f) ? t : NEG * t;
    }
    float m = fmaxf(e0, e1);
#pragma unroll
    for (int off = 32; off; off >>= 1) m = fmaxf(m, __shfl_xor(m, off));
    float p0 = (j0 < deg) ? __expf(e0 - m) : 0.f;
    float p1 = (j1 < deg) ? __expf(e1 - m) : 0.f;
    float s = p0 + p1;
#pragma unroll
    for (int off = 32; off; off >>= 1) s += __shfl_xor(s, off);
    float inv = 1.f / s;
    float a0 = p0 * inv, a1 = p1 * inv;

    int slot = lane >> 3, r = lane & 7;
    float acc[16];
#pragma unroll
    for (int k = 0; k < 16; ++k) acc[k] = 0.f;

    for (int base = 0; base < deg; base += 8) {
        int idx = base + slot;
        int lsrc = idx & 63;
        float alA = __shfl(a0, lsrc);
        float alB = __shfl(a1, lsrc);
        int   sjA = __shfl(s0, lsrc);
        int   sjB = __shfl(s1, lsrc);
        bool ok = idx < deg;
        float al = ok ? ((idx < 64) ? alA : alB) : 0.f;
        int   sj = ok ? ((idx < 64) ? sjA : sjB) : 0;
        const float4* hp = (const float4*)&h[(size_t)sj * 128 + r * 16];
        float4 v0 = hp[0];
        float4 v1 = hp[1];
        float4 v2 = hp[2];
        float4 v3 = hp[3];
        acc[0]  = fmaf(al, v0.x, acc[0]);
        acc[1]  = fmaf(al, v0.y, acc[1]);
        acc[2]  = fmaf(al, v0.z, acc[2]);
        acc[3]  = fmaf(al, v0.w, acc[3]);
        acc[4]  = fmaf(al, v1.x, acc[4]);
        acc[5]  = fmaf(al, v1.y, acc[5]);
        acc[6]  = fmaf(al, v1.z, acc[6]);
        acc[7]  = fmaf(al, v1.w, acc[7]);
        acc[8]  = fmaf(al, v2.x, acc[8]);
        acc[9]  = fmaf(al, v2.y, acc[9]);
        acc[10] = fmaf(al, v2.z, acc[10]);
        acc[11] = fmaf(al, v2.w, acc[11]);
        acc[12] = fmaf(al, v3.x, acc[12]);
        acc[13] = fmaf(al, v3.y, acc[13]);
        acc[14] = fmaf(al, v3.z, acc[14]);
        acc[15] = fmaf(al, v3.w, acc[15]);
    }
#pragma unroll
    for (int k = 0; k < 16; ++k) {
        acc[k] += __shfl_xor(acc[k], 8);
        acc[k] += __shfl_xor(acc[k], 16);
        acc[k] += __shfl_xor(acc[k], 32);
    }
    if (slot == 0) {
        float o[16];
#pragma unroll
        for (int k = 0; k < 16; ++k) o[k] = fmaxf(acc[k] + bias[r * 16 + k], 0.f);
        float4* op = (float4*)&outp[(size_t)d * 128 + r * 16];
        op[0] = make_float4(o[0],  o[1],  o[2],  o[3]);
        op[1] = make_float4(o[4],  o[5],  o[6],  o[7]);
        op[2] = make_float4(o[8],  o[9],  o[10], o[11]);
        op[3] = make_float4(o[12], o[13], o[14], o[15]);
    }
}

// ---------------- GCN aggregation ----------------

__global__ __launch_bounds__(256) void k_gcn_agg(const float* __restrict__ h,
                                                 const int* __restrict__ cnt,
                                                 const u16* __restrict__ csr,
                                                 const float* __restrict__ bias,
                                                 float* __restrict__ z) {
    int lane = threadIdx.x & 63, wv = threadIdx.x >> 6;
    int d = blockIdx.x * 4 + wv;
    if (d >= NN) return;
    int degc = cnt[d];
    int deg = degc > CAP ? CAP : degc;
    float did = rsqrtf((float)degc);
    const u16* rowp = csr + (size_t)d * CAP;

    int j0 = lane, j1 = lane + 64;
    int s0 = 0, s1 = 0;
    float n0 = 0.f, n1 = 0.f;
    if (j0 < deg) { s0 = rowp[j0]; n0 = rsqrtf((float)cnt[s0]) * did; }
    if (j1 < deg) { s1 = rowp[j1]; n1 = rsqrtf((float)cnt[s1]) * did; }

    int slot = lane >> 3, r = lane & 7;
    float acc[8];
#pragma unroll
    for (int k = 0; k < 8; ++k) acc[k] = 0.f;

    for (int base = 0; base < deg; base += 8) {
        int idx = base + slot;
        int lsrc = idx & 63;
        float nA = __shfl(n0, lsrc);
        float nB = __shfl(n1, lsrc);
        int  sjA = __shfl(s0, lsrc);
        int  sjB = __shfl(s1, lsrc);
        bool ok = idx < deg;
        float nm = ok ? ((idx < 64) ? nA : nB) : 0.f;
        int   sj = ok ? ((idx < 64) ? sjA : sjB) : 0;
        const float4* hp = (const float4*)&h[(size_t)sj * 64 + r * 8];
        float4 v0 = hp[0];
        float4 v1 = hp[1];
        acc[0] = fmaf(nm, v0.x, acc[0]);
        acc[1] = fmaf(nm, v0.y, acc[1]);
        acc[2] = fmaf(nm, v0.z, acc[2]);
        acc[3] = fmaf(nm, v0.w, acc[3]);
        acc[4] = fmaf(nm, v1.x, acc[4]);
        acc[5] = fmaf(nm, v1.y, acc[5]);
        acc[6] = fmaf(nm, v1.z, acc[6]);
        acc[7] = fmaf(nm, v1.w, acc[7]);
    }
#pragma unroll
    for (int k = 0; k < 8; ++k) {
        acc[k] += __shfl_xor(acc[k], 8);
        acc[k] += __shfl_xor(acc[k], 16);
        acc[k] += __shfl_xor(acc[k], 32);
    }
    if (slot == 0) {
        float4 b0 = *(const float4*)&bias[r * 8];
        float4 b1 = *(const float4*)&bias[r * 8 + 4];
        float4* zp = (float4*)&z[(size_t)d * 64 + r * 8];
        zp[0] = make_float4(acc[0] + b0.x, acc[1] + b0.y, acc[2] + b0.z, acc[3] + b0.w);
        zp[1] = make_float4(acc[4] + b1.x, acc[5] + b1.y, acc[6] + b1.z, acc[7] + b1.w);
    }
}

// ---------------- link decode ----------------

__global__ __launch_bounds__(256) void k_decode(const float* __restrict__ z,
                                                const int* __restrict__ eli,
                                                float* __restrict__ outp) {
    int lane = threadIdx.x & 63, wv = threadIdx.x >> 6;
    int g = lane >> 4, r = lane & 15;
    int idx = (blockIdx.x * 4 + wv) * 4 + g;
    if (idx >= NLBL) return;
    int a = eli[idx], b = eli[NLBL + idx];
    float4 za = *(const float4*)&z[(size_t)a * 64 + r * 4];
    float4 zb = *(const float4*)&z[(size_t)b * 64 + r * 4];
    float v = za.x * zb.x + za.y * zb.y + za.z * zb.z + za.w * zb.w;
#pragma unroll
    for (int off = 8; off; off >>= 1) v += __shfl_xor(v, off);
    if (r == 0) outp[idx] = v;
}

// ---------------- launch ----------------

extern "C" void kernel_launch(void* const* d_in, const int* in_sizes, int n_in,
                              void* d_out, int out_size, void* d_ws, size_t ws_size,
                              hipStream_t stream) {
    const float* x   = (const float*)d_in[0];
    const int*   ei  = (const int*)d_in[1];
    const int*   eli = (const int*)d_in[2];
    const float* W1 = (const float*)d_in[3];
    const float* a1s = (const float*)d_in[4];
    const float* a1d = (const float*)d_in[5];
    const float* b1 = (const float*)d_in[6];
    const float* W2 = (const float*)d_in[7];
    const float* a2s = (const float*)d_in[8];
    const float* a2d = (const float*)d_in[9];
    const float* b2 = (const float*)d_in[10];
    const float* W3 = (const float*)d_in[11];
    const float* a3s = (const float*)d_in[12];
    const float* a3d = (const float*)d_in[13];
    const float* b3 = (const float*)d_in[14];
    const float* W4 = (const float*)d_in[15];
    const float* b4 = (const float*)d_in[16];
    float* outp = (float*)d_out;

    char* p = (char*)d_ws;
    auto alloc = [&](size_t bytes) -> char* {
        char* r = p;
        p += (bytes + 255) & ~(size_t)255;
        return r;
    };
    int*   cnt  = (int*)alloc((size_t)NN * 4);
    u16*   csr  = (u16*)alloc((size_t)NN * CAP * 2);
    int*   gcnt = (int*)alloc((size_t)NBK * 4);
    float* asv  = (float*)alloc((size_t)NN * 4);
    float* advv = (float*)alloc((size_t)NN * 4);
    float* G    = (float*)alloc((size_t)NN * 128 * 4);
    float* Bu1  = (float*)alloc((size_t)NN * 128 * 4);
    float* Bu2  = (float*)alloc((size_t)NN * 128 * 4);
    unsigned* bins = (unsigned*)Bu2;   // alias: bins dead before Bu2 first written

    const int gBin  = (NE + CHK - 1) / CHK;
    const int gGemm = (NN + 63) / 64;
    const int gNode = (NN + 3) / 4;
    const int gDec  = (NLBL + 15) / 16;

    k_zero<<<1, 256, 0, stream>>>(gcnt);
    k_bin<<<gBin, 256, 0, stream>>>(ei, gcnt, bins);
    k_build<<<NBK, 256, 0, stream>>>(bins, gcnt, cnt, csr);

    gemm_k<128, true><<<gGemm, 256, 0, stream>>>(x, W1, G, a1s, a1d, asv, advv, NN);
    k_gat_agg<<<gNode, 256, 0, stream>>>(G, cnt, csr, asv, advv, b1, Bu1);

    gemm_k<128, true><<<gGemm, 256, 0, stream>>>(Bu1, W2, G, a2s, a2d, asv, advv, NN);
    k_gat_agg<<<gNode, 256, 0, stream>>>(G, cnt, csr, asv, advv, b2, Bu2);

    gemm_k<128, true><<<gGemm, 256, 0, stream>>>(Bu2, W3, G, a3s, a3d, asv, advv, NN);
    k_gat_agg<<<gNode, 256, 0, stream>>>(G, cnt, csr, asv, advv, b3, Bu1);

    gemm_k<64, false><<<gGemm, 256, 0, stream>>>(Bu1, W4, G, nullptr, nullptr, nullptr, nullptr, NN);
    k_gcn_agg<<<gNode, 256, 0, stream>>>(G, cnt, csr, b4, Bu2);

    k_decode<<<gDec, 256, 0, stream>>>(Bu2, eli, outp);
}

// Round 7
// 455.558 us; speedup vs baseline: 1.7465x; 1.7465x over previous
//
#include <hip/hip_runtime.h>
#include <hip/hip_fp16.h>
#include <math.h>

#define NN   50000
#define NE   1600000
#define DHID 128
#define DOUTC 64
#define NLBL 200000
#define CAP  80          // max in-degree+1; Poisson(32): P(deg>=80) ~ 1e-12/node
#define NEG  0.2f
#define NBK  196         // ceil(50000/256) dst buckets of 256 nodes
#define CAPB 8800        // bucket capacity: Poisson(8163) + 7 sigma
#define CHK  4096        // edges per k_bin block

typedef unsigned short u16;

// ---------------- CSR build: binned counting sort (R4 version — sort experiment reverted) ----------------

__global__ __launch_bounds__(256) void k_zero(int* __restrict__ gcnt) {
    int i = threadIdx.x;
    if (i < NBK) gcnt[i] = 0;
}

__global__ __launch_bounds__(256) void k_bin(const int* __restrict__ ei,
                                             int* __restrict__ gcnt,
                                             unsigned* __restrict__ bins) {
    __shared__ int cntL[NBK];
    __shared__ int curL[NBK];
    const int tid = threadIdx.x;
    const int e0 = blockIdx.x * CHK + tid * 16;
    const bool act = (e0 + 15) < NE;

    unsigned pk[16];
    int bb[16];
    if (act) {
#pragma unroll
        for (int g = 0; g < 4; ++g) {
            int4 s4 = *(const int4*)&ei[e0 + g * 4];
            int4 d4 = *(const int4*)&ei[NE + e0 + g * 4];
            int sa[4] = {s4.x, s4.y, s4.z, s4.w};
            int da[4] = {d4.x, d4.y, d4.z, d4.w};
#pragma unroll
            for (int k = 0; k < 4; ++k) {
                int idx = g * 4 + k;
                bb[idx] = da[k] >> 8;
                pk[idx] = (unsigned)sa[k] | ((unsigned)(da[k] & 255) << 16);
            }
        }
    }
    for (int i = tid; i < NBK; i += 256) cntL[i] = 0;
    __syncthreads();
    if (act) {
#pragma unroll
        for (int k = 0; k < 16; ++k) atomicAdd(&cntL[bb[k]], 1);
    }
    __syncthreads();
    for (int i = tid; i < NBK; i += 256) curL[i] = atomicAdd(&gcnt[i], cntL[i]);
    __syncthreads();
    if (act) {
#pragma unroll
        for (int k = 0; k < 16; ++k) {
            int off = atomicAdd(&curL[bb[k]], 1);
            bins[(size_t)bb[k] * CAPB + off] = pk[k];
        }
    }
}

__global__ __launch_bounds__(256) void k_build(const unsigned* __restrict__ bins,
                                               const int* __restrict__ gcnt,
                                               int* __restrict__ cnt,
                                               u16* __restrict__ csr) {
    __shared__ u16 rows[256 * CAP];   // 40 KB
    __shared__ int cur[256];
    const int b = blockIdx.x, tid = threadIdx.x;
    const int d0 = b << 8;
    const int nd = min(256, NN - d0);
    if (tid < nd) { cur[tid] = 1; rows[tid * CAP] = (u16)(d0 + tid); }  // self-loop slot 0
    __syncthreads();
    const int n = gcnt[b];
    for (int i = tid; i < n; i += 256) {
        unsigned v = bins[(size_t)b * CAPB + i];
        int s = v & 0xFFFF, dl = v >> 16;
        int pos = atomicAdd(&cur[dl], 1);
        if (pos < CAP) rows[dl * CAP + pos] = (u16)s;
    }
    __syncthreads();
    const unsigned* rw = (const unsigned*)rows;
    unsigned* cw = (unsigned*)(csr + (size_t)d0 * CAP);
    const int tot = nd * (CAP / 2);
    for (int i = tid; i < tot; i += 256) cw[i] = rw[i];
    if (tid < nd) cnt[d0 + tid] = cur[tid];
}

// ---------------- fp32 GEMM -> fp16 gather table, fused attn dots ----------------
// C16 is fp16 (halves gather bytes; accumulation downstream stays fp32).

template <int NOUT, bool ATTN>
__global__ __launch_bounds__(256) void gemm_k(const float* __restrict__ A,
                                              const float* __restrict__ W,
                                              __half* __restrict__ C16,
                                              const float* __restrict__ a_s,
                                              const float* __restrict__ a_d,
                                              float* __restrict__ asv,
                                              float* __restrict__ adv, int M) {
    constexpr int BM = 64, BK = 32, TM = 4, TN = NOUT / 16;
    __shared__ float As[BM][36];
    __shared__ float Ws[BK][NOUT];
    const int tid = threadIdx.x;
    const int tx = tid & 15, ty = tid >> 4;
    const int row0 = blockIdx.x * BM;

    float acc[TM][TN];
#pragma unroll
    for (int i = 0; i < TM; ++i)
#pragma unroll
        for (int j = 0; j < TN; ++j) acc[i][j] = 0.f;

    for (int k0 = 0; k0 < 128; k0 += BK) {
        {
            int r = tid >> 3;
            int c = (tid & 7) * 4;
#pragma unroll
            for (int rr = 0; rr < BM; rr += 32) {
                int grow = row0 + r + rr;
                float4 v = make_float4(0.f, 0.f, 0.f, 0.f);
                if (grow < M) v = *(const float4*)&A[(size_t)grow * 128 + k0 + c];
                *(float4*)&As[r + rr][c] = v;
            }
        }
        {
            constexpr int TOT4 = BK * NOUT / 4;
#pragma unroll
            for (int i4 = tid; i4 < TOT4; i4 += 256) {
                int kk = (i4 * 4) / NOUT;
                int cc = (i4 * 4) % NOUT;
                *(float4*)&Ws[kk][cc] = *(const float4*)&W[(size_t)(k0 + kk) * NOUT + cc];
            }
        }
        __syncthreads();
#pragma unroll
        for (int k4 = 0; k4 < BK; k4 += 4) {
            float a4[TM][4];
#pragma unroll
            for (int i = 0; i < TM; ++i) {
                float4 v = *(const float4*)&As[ty * TM + i][k4];
                a4[i][0] = v.x; a4[i][1] = v.y; a4[i][2] = v.z; a4[i][3] = v.w;
            }
#pragma unroll
            for (int kk = 0; kk < 4; ++kk) {
                int k = k4 + kk;
                float rw[TN];
                if (NOUT == 128) {
                    float4 w0 = *(const float4*)&Ws[k][tx * 4];
                    float4 w1 = *(const float4*)&Ws[k][64 + tx * 4];
                    rw[0] = w0.x; rw[1] = w0.y; rw[2] = w0.z; rw[3] = w0.w;
                    rw[4] = w1.x; rw[5] = w1.y; rw[6] = w1.z; rw[7] = w1.w;
                } else {
                    float4 w0 = *(const float4*)&Ws[k][tx * 4];
                    rw[0] = w0.x; rw[1] = w0.y; rw[2] = w0.z; rw[3] = w0.w;
                }
#pragma unroll
                for (int i = 0; i < TM; ++i)
#pragma unroll
                    for (int j = 0; j < TN; ++j) acc[i][j] = fmaf(a4[i][kk], rw[j], acc[i][j]);
            }
        }
        __syncthreads();
    }
#pragma unroll
    for (int i = 0; i < TM; ++i) {
        int grow = row0 + ty * TM + i;
        if (grow < M) {
            __half2 p0 = __floats2half2_rn(acc[i][0], acc[i][1]);
            __half2 p1 = __floats2half2_rn(acc[i][2], acc[i][3]);
            __half2* cp = (__half2*)&C16[(size_t)grow * NOUT + tx * 4];
            cp[0] = p0; cp[1] = p1;
            if (NOUT == 128) {
                __half2 p2 = __floats2half2_rn(acc[i][4], acc[i][5]);
                __half2 p3 = __floats2half2_rn(acc[i][6], acc[i][7]);
                __half2* cq = (__half2*)&C16[(size_t)grow * NOUT + 64 + tx * 4];
                cq[0] = p2; cq[1] = p3;
            }
        }
    }
    if (ATTN) {
        float4 s0 = *(const float4*)&a_s[tx * 4];
        float4 s1 = *(const float4*)&a_s[64 + tx * 4];
        float4 d0 = *(const float4*)&a_d[tx * 4];
        float4 d1 = *(const float4*)&a_d[64 + tx * 4];
#pragma unroll
        for (int i = 0; i < TM; ++i) {
            float ps = acc[i][0] * s0.x + acc[i][1] * s0.y + acc[i][2] * s0.z + acc[i][3] * s0.w
                     + acc[i][4] * s1.x + acc[i][5] * s1.y + acc[i][6] * s1.z + acc[i][7] * s1.w;
            float pd = acc[i][0] * d0.x + acc[i][1] * d0.y + acc[i][2] * d0.z + acc[i][3] * d0.w
                     + acc[i][4] * d1.x + acc[i][5] * d1.y + acc[i][6] * d1.z + acc[i][7] * d1.w;
#pragma unroll
            for (int off = 1; off < 16; off <<= 1) {
                ps += __shfl_xor(ps, off);
                pd += __shfl_xor(pd, off);
            }
            int grow = row0 + ty * TM + i;
            if (tx == 0 && grow < M) { asv[grow] = ps; adv[grow] = pd; }
        }
    }
}

// fma 8 halves (one uint4) scaled by al into acc[0..7]
__device__ inline void fma_h8(uint4 u, float al, float* acc) {
    float2 f0 = __half22float2(*(__half2*)&u.x);
    float2 f1 = __half22float2(*(__half2*)&u.y);
    float2 f2 = __half22float2(*(__half2*)&u.z);
    float2 f3 = __half22float2(*(__half2*)&u.w);
    acc[0] = fmaf(al, f0.x, acc[0]);
    acc[1] = fmaf(al, f0.y, acc[1]);
    acc[2] = fmaf(al, f1.x, acc[2]);
    acc[3] = fmaf(al, f1.y, acc[3]);
    acc[4] = fmaf(al, f2.x, acc[4]);
    acc[5] = fmaf(al, f2.y, acc[5]);
    acc[6] = fmaf(al, f3.x, acc[6]);
    acc[7] = fmaf(al, f3.y, acc[7]);
}

// ---------------- GAT aggregation: fp16 gather, 8 edge-slots x 8 lanes ----------------

__global__ __launch_bounds__(256) void k_gat_agg(const __half* __restrict__ h,
                                                 const int* __restrict__ cnt,
                                                 const u16* __restrict__ csr,
                                                 const float* __restrict__ asv,
                                                 const float* __restrict__ adv,
                                                 const float* __restrict__ bias,
                                                 float* __restrict__ outp) {
    int lane = threadIdx.x & 63, wv = threadIdx.x >> 6;
    int d = blockIdx.x * 4 + wv;
    if (d >= NN) return;
    int deg = cnt[d]; if (deg > CAP) deg = CAP;
    const float advd = adv[d];
    const u16* rowp = csr + (size_t)d * CAP;

    // ---- phase A: exact softmax over <=80 edges in 2 register chunks ----
    int j0 = lane, j1 = lane + 64;
    int s0 = 0, s1 = 0;
    float e0 = -INFINITY, e1 = -INFINITY;
    if (j0 < deg) {
        s0 = rowp[j0];
        float t = asv[s0] + advd;
        e0 = (t >= 0.f) ? t : NEG * t;
    }
    if (j1 < deg) {
        s1 = rowp[j1];
        float t = asv[s1] + advd;
        e1 = (t >= 0.f) ? t : NEG * t;
    }
    float m = fmaxf(e0, e1);
#pragma unroll
    for (int off = 32; off; off >>= 1) m = fmaxf(m, __shfl_xor(m, off));
    float p0 = (j0 < deg) ? __expf(e0 - m) : 0.f;
    float p1 = (j1 < deg) ? __expf(e1 - m) : 0.f;
    float s = p0 + p1;
#pragma unroll
    for (int off = 32; off; off >>= 1) s += __shfl_xor(s, off);
    float inv = 1.f / s;
    float a0 = p0 * inv, a1 = p1 * inv;

    // ---- phase B: 8 edge-slots, lane r owns 16 cols (2 x uint4 of halves) ----
    int slot = lane >> 3, r = lane & 7;
    float acc[16];
#pragma unroll
    for (int k = 0; k < 16; ++k) acc[k] = 0.f;

    for (int base = 0; base < deg; base += 8) {
        int idx = base + slot;
        int lsrc = idx & 63;
        float alA = __shfl(a0, lsrc);
        float alB = __shfl(a1, lsrc);
        int   sjA = __shfl(s0, lsrc);
        int   sjB = __shfl(s1, lsrc);
        bool ok = idx < deg;
        float al = ok ? ((idx < 64) ? alA : alB) : 0.f;
        int   sj = ok ? ((idx < 64) ? sjA : sjB) : 0;
        const uint4* hp = (const uint4*)&h[(size_t)sj * 128 + r * 16];
        uint4 ua = hp[0];
        uint4 ub = hp[1];
        fma_h8(ua, al, acc);
        fma_h8(ub, al, acc + 8);
    }
#pragma unroll
    for (int k = 0; k < 16; ++k) {
        acc[k] += __shfl_xor(acc[k], 8);
        acc[k] += __shfl_xor(acc[k], 16);
        acc[k] += __shfl_xor(acc[k], 32);
    }
    if (slot == 0) {
        float o[16];
#pragma unroll
        for (int k = 0; k < 16; ++k) o[k] = fmaxf(acc[k] + bias[r * 16 + k], 0.f);
        float4* op = (float4*)&outp[(size_t)d * 128 + r * 16];
        op[0] = make_float4(o[0],  o[1],  o[2],  o[3]);
        op[1] = make_float4(o[4],  o[5],  o[6],  o[7]);
        op[2] = make_float4(o[8],  o[9],  o[10], o[11]);
        op[3] = make_float4(o[12], o[13], o[14], o[15]);
    }
}

// ---------------- GCN aggregation: fp16 gather ----------------

__global__ __launch_bounds__(256) void k_gcn_agg(const __half* __restrict__ h,
                                                 const int* __restrict__ cnt,
                                                 const u16* __restrict__ csr,
                                                 const float* __restrict__ bias,
                                                 float* __restrict__ z) {
    int lane = threadIdx.x & 63, wv = threadIdx.x >> 6;
    int d = blockIdx.x * 4 + wv;
    if (d >= NN) return;
    int degc = cnt[d];
    int deg = degc > CAP ? CAP : degc;
    float did = rsqrtf((float)degc);
    const u16* rowp = csr + (size_t)d * CAP;

    int j0 = lane, j1 = lane + 64;
    int s0 = 0, s1 = 0;
    float n0 = 0.f, n1 = 0.f;
    if (j0 < deg) { s0 = rowp[j0]; n0 = rsqrtf((float)cnt[s0]) * did; }
    if (j1 < deg) { s1 = rowp[j1]; n1 = rsqrtf((float)cnt[s1]) * did; }

    int slot = lane >> 3, r = lane & 7;
    float acc[8];
#pragma unroll
    for (int k = 0; k < 8; ++k) acc[k] = 0.f;

    for (int base = 0; base < deg; base += 8) {
        int idx = base + slot;
        int lsrc = idx & 63;
        float nA = __shfl(n0, lsrc);
        float nB = __shfl(n1, lsrc);
        int  sjA = __shfl(s0, lsrc);
        int  sjB = __shfl(s1, lsrc);
        bool ok = idx < deg;
        float nm = ok ? ((idx < 64) ? nA : nB) : 0.f;
        int   sj = ok ? ((idx < 64) ? sjA : sjB) : 0;
        uint4 u = *(const uint4*)&h[(size_t)sj * 64 + r * 8];
        fma_h8(u, nm, acc);
    }
#pragma unroll
    for (int k = 0; k < 8; ++k) {
        acc[k] += __shfl_xor(acc[k], 8);
        acc[k] += __shfl_xor(acc[k], 16);
        acc[k] += __shfl_xor(acc[k], 32);
    }
    if (slot == 0) {
        float4 b0 = *(const float4*)&bias[r * 8];
        float4 b1 = *(const float4*)&bias[r * 8 + 4];
        float4* zp = (float4*)&z[(size_t)d * 64 + r * 8];
        zp[0] = make_float4(acc[0] + b0.x, acc[1] + b0.y, acc[2] + b0.z, acc[3] + b0.w);
        zp[1] = make_float4(acc[4] + b1.x, acc[5] + b1.y, acc[6] + b1.z, acc[7] + b1.w);
    }
}

// ---------------- link decode ----------------

__global__ __launch_bounds__(256) void k_decode(const float* __restrict__ z,
                                                const int* __restrict__ eli,
                                                float* __restrict__ outp) {
    int lane = threadIdx.x & 63, wv = threadIdx.x >> 6;
    int g = lane >> 4, r = lane & 15;
    int idx = (blockIdx.x * 4 + wv) * 4 + g;
    if (idx >= NLBL) return;
    int a = eli[idx], b = eli[NLBL + idx];
    float4 za = *(const float4*)&z[(size_t)a * 64 + r * 4];
    float4 zb = *(const float4*)&z[(size_t)b * 64 + r * 4];
    float v = za.x * zb.x + za.y * zb.y + za.z * zb.z + za.w * zb.w;
#pragma unroll
    for (int off = 8; off; off >>= 1) v += __shfl_xor(v, off);
    if (r == 0) outp[idx] = v;
}

// ---------------- launch ----------------

extern "C" void kernel_launch(void* const* d_in, const int* in_sizes, int n_in,
                              void* d_out, int out_size, void* d_ws, size_t ws_size,
                              hipStream_t stream) {
    const float* x   = (const float*)d_in[0];
    const int*   ei  = (const int*)d_in[1];
    const int*   eli = (const int*)d_in[2];
    const float* W1 = (const float*)d_in[3];
    const float* a1s = (const float*)d_in[4];
    const float* a1d = (const float*)d_in[5];
    const float* b1 = (const float*)d_in[6];
    const float* W2 = (const float*)d_in[7];
    const float* a2s = (const float*)d_in[8];
    const float* a2d = (const float*)d_in[9];
    const float* b2 = (const float*)d_in[10];
    const float* W3 = (const float*)d_in[11];
    const float* a3s = (const float*)d_in[12];
    const float* a3d = (const float*)d_in[13];
    const float* b3 = (const float*)d_in[14];
    const float* W4 = (const float*)d_in[15];
    const float* b4 = (const float*)d_in[16];
    float* outp = (float*)d_out;

    char* p = (char*)d_ws;
    auto alloc = [&](size_t bytes) -> char* {
        char* r = p;
        p += (bytes + 255) & ~(size_t)255;
        return r;
    };
    int*   cnt  = (int*)alloc((size_t)NN * 4);
    u16*   csr  = (u16*)alloc((size_t)NN * CAP * 2);
    int*   gcnt = (int*)alloc((size_t)NBK * 4);
    float* asv  = (float*)alloc((size_t)NN * 4);
    float* advv = (float*)alloc((size_t)NN * 4);
    __half* G   = (__half*)alloc((size_t)NN * 128 * 2);   // fp16 gather table
    float* Bu1  = (float*)alloc((size_t)NN * 128 * 4);
    float* Bu2  = (float*)alloc((size_t)NN * 128 * 4);
    unsigned* bins = (unsigned*)Bu2;   // alias: bins dead before Bu2 first written

    const int gBin  = (NE + CHK - 1) / CHK;
    const int gGemm = (NN + 63) / 64;
    const int gNode = (NN + 3) / 4;
    const int gDec  = (NLBL + 15) / 16;

    k_zero<<<1, 256, 0, stream>>>(gcnt);
    k_bin<<<gBin, 256, 0, stream>>>(ei, gcnt, bins);
    k_build<<<NBK, 256, 0, stream>>>(bins, gcnt, cnt, csr);

    gemm_k<128, true><<<gGemm, 256, 0, stream>>>(x, W1, G, a1s, a1d, asv, advv, NN);
    k_gat_agg<<<gNode, 256, 0, stream>>>(G, cnt, csr, asv, advv, b1, Bu1);

    gemm_k<128, true><<<gGemm, 256, 0, stream>>>(Bu1, W2, G, a2s, a2d, asv, advv, NN);
    k_gat_agg<<<gNode, 256, 0, stream>>>(G, cnt, csr, asv, advv, b2, Bu2);

    gemm_k<128, true><<<gGemm, 256, 0, stream>>>(Bu2, W3, G, a3s, a3d, asv, advv, NN);
    k_gat_agg<<<gNode, 256, 0, stream>>>(G, cnt, csr, asv, advv, b3, Bu1);

    gemm_k<64, false><<<gGemm, 256, 0, stream>>>(Bu1, W4, G, nullptr, nullptr, nullptr, nullptr, NN);
    k_gcn_agg<<<gNode, 256, 0, stream>>>(G, cnt, csr, b4, Bu2);

    k_decode<<<gDec, 256, 0, stream>>>(Bu2, eli, outp);
}

// Round 8
// 444.066 us; speedup vs baseline: 1.7917x; 1.0259x over previous
//
#include <hip/hip_runtime.h>
#include <hip/hip_fp16.h>
#include <math.h>

#define NN   50000
#define NE   1600000
#define DHID 128
#define DOUTC 64
#define NLBL 200000
#define CAP  80          // max in-degree+1; Poisson(32): P(deg>=80) ~ 1e-12/node
#define NEG  0.2f
#define NBK  196         // ceil(50000/256) dst buckets of 256 nodes
#define CAPB 8800        // bucket capacity: Poisson(8163) + 7 sigma
#define CHK  4096        // edges per k_bin block

typedef unsigned short u16;
typedef _Float16 half8 __attribute__((ext_vector_type(8)));
typedef float floatx4 __attribute__((ext_vector_type(4)));

// ---------------- CSR build: binned counting sort ----------------

__global__ __launch_bounds__(256) void k_zero(int* __restrict__ gcnt) {
    int i = threadIdx.x;
    if (i < NBK) gcnt[i] = 0;
}

__global__ __launch_bounds__(256) void k_bin(const int* __restrict__ ei,
                                             int* __restrict__ gcnt,
                                             unsigned* __restrict__ bins) {
    __shared__ int cntL[NBK];
    __shared__ int curL[NBK];
    const int tid = threadIdx.x;
    const int e0 = blockIdx.x * CHK + tid * 16;
    const bool act = (e0 + 15) < NE;

    unsigned pk[16];
    int bb[16];
    if (act) {
#pragma unroll
        for (int g = 0; g < 4; ++g) {
            int4 s4 = *(const int4*)&ei[e0 + g * 4];
            int4 d4 = *(const int4*)&ei[NE + e0 + g * 4];
            int sa[4] = {s4.x, s4.y, s4.z, s4.w};
            int da[4] = {d4.x, d4.y, d4.z, d4.w};
#pragma unroll
            for (int k = 0; k < 4; ++k) {
                int idx = g * 4 + k;
                bb[idx] = da[k] >> 8;
                pk[idx] = (unsigned)sa[k] | ((unsigned)(da[k] & 255) << 16);
            }
        }
    }
    for (int i = tid; i < NBK; i += 256) cntL[i] = 0;
    __syncthreads();
    if (act) {
#pragma unroll
        for (int k = 0; k < 16; ++k) atomicAdd(&cntL[bb[k]], 1);
    }
    __syncthreads();
    for (int i = tid; i < NBK; i += 256) curL[i] = atomicAdd(&gcnt[i], cntL[i]);
    __syncthreads();
    if (act) {
#pragma unroll
        for (int k = 0; k < 16; ++k) {
            int off = atomicAdd(&curL[bb[k]], 1);
            bins[(size_t)bb[k] * CAPB + off] = pk[k];
        }
    }
}

__global__ __launch_bounds__(256) void k_build(const unsigned* __restrict__ bins,
                                               const int* __restrict__ gcnt,
                                               int* __restrict__ cnt,
                                               u16* __restrict__ csr) {
    __shared__ u16 rows[256 * CAP];   // 40 KB
    __shared__ int cur[256];
    const int b = blockIdx.x, tid = threadIdx.x;
    const int d0 = b << 8;
    const int nd = min(256, NN - d0);
    if (tid < nd) { cur[tid] = 1; rows[tid * CAP] = (u16)(d0 + tid); }  // self-loop slot 0
    __syncthreads();
    const int n = gcnt[b];
    for (int i = tid; i < n; i += 256) {
        unsigned v = bins[(size_t)b * CAPB + i];
        int s = v & 0xFFFF, dl = v >> 16;
        int pos = atomicAdd(&cur[dl], 1);
        if (pos < CAP) rows[dl * CAP + pos] = (u16)s;
    }
    __syncthreads();
    const unsigned* rw = (const unsigned*)rows;
    unsigned* cw = (unsigned*)(csr + (size_t)d0 * CAP);
    const int tot = nd * (CAP / 2);
    for (int i = tid; i < tot; i += 256) cw[i] = rw[i];
    if (tid < nd) cnt[d0 + tid] = cur[tid];
}

// ---------------- cast x fp32 -> fp16 ----------------

__global__ __launch_bounds__(256) void k_cast(const float* __restrict__ x,
                                              __half* __restrict__ x16) {
    int i = (blockIdx.x * 256 + threadIdx.x) * 4;
    if (i < NN * 128) {
        float4 v = *(const float4*)&x[i];
        __half2 h0 = __floats2half2_rn(v.x, v.y);
        __half2 h1 = __floats2half2_rn(v.z, v.w);
        uint2 u;
        __builtin_memcpy(&u.x, &h0, 4);
        __builtin_memcpy(&u.y, &h1, 4);
        *(uint2*)&x16[i] = u;
    }
}

// ---------------- MFMA fp16 GEMM: C16[M,NOUT] = A16[M,128] @ W[128,NOUT] ----------------
// mfma_f32_16x16x32_f16 layouts (m89/m120-verified):
//   A frag: lane holds A[m=lane&15][k=quad*8+j], j=0..7 (8 contiguous halves)
//   B frag: lane holds B[k=quad*8+j][n=lane&15]  -> contiguous in W-transposed
//   D frag: D[row=quad*4+reg][col=lane&15], 4 fp32 regs
// Block: 4 waves x 16 rows = 64 rows; each wave does all NOUT cols.

template <int NOUT, bool ATTN>
__global__ __launch_bounds__(256) void gemm_mfma(const __half* __restrict__ A16,
                                                 const float* __restrict__ W,
                                                 __half* __restrict__ C16,
                                                 const float* __restrict__ a_s,
                                                 const float* __restrict__ a_d,
                                                 float* __restrict__ asv,
                                                 float* __restrict__ adv, int M) {
    constexpr int CT = NOUT / 16;
    __shared__ _Float16 Wt[NOUT][136];   // transposed W, +8 pad: b128 reads 2-way (free)
    const int tid = threadIdx.x;
    // stage W transposed (fp32 coalesced read, fp16 scattered LDS write; one-time)
    for (int i4 = tid; i4 < 128 * NOUT / 4; i4 += 256) {
        int i = i4 * 4;
        int k = i / NOUT, n = i % NOUT;
        float4 w = *(const float4*)&W[i];
        Wt[n + 0][k] = (_Float16)w.x;
        Wt[n + 1][k] = (_Float16)w.y;
        Wt[n + 2][k] = (_Float16)w.z;
        Wt[n + 3][k] = (_Float16)w.w;
    }
    __syncthreads();

    const int wave = tid >> 6, lane = tid & 63;
    const int n = lane & 15, quad = lane >> 4;
    const int row0 = blockIdx.x * 64 + wave * 16;

    // A fragments for 4 k-steps
    half8 a[4];
    const bool rowok = (row0 + n) < M;
    const _Float16* Ap = (const _Float16*)A16 + (size_t)(row0 + n) * 128 + quad * 8;
    half8 zz = {};
#pragma unroll
    for (int ks = 0; ks < 4; ++ks)
        a[ks] = rowok ? *(const half8*)(Ap + ks * 32) : zz;

    floatx4 acc[CT];
#pragma unroll
    for (int c = 0; c < CT; ++c) acc[c] = (floatx4){0.f, 0.f, 0.f, 0.f};

#pragma unroll
    for (int c = 0; c < CT; ++c) {
#pragma unroll
        for (int ks = 0; ks < 4; ++ks) {
            half8 b = *(const half8*)&Wt[c * 16 + n][ks * 32 + quad * 8];
            acc[c] = __builtin_amdgcn_mfma_f32_16x16x32_f16(a[ks], b, acc[c], 0, 0, 0);
        }
    }

    // store h fp16
#pragma unroll
    for (int c = 0; c < CT; ++c) {
#pragma unroll
        for (int reg = 0; reg < 4; ++reg) {
            int row = row0 + quad * 4 + reg;
            if (row < M) C16[(size_t)row * NOUT + c * 16 + n] = __float2half(acc[c][reg]);
        }
    }

    if (ATTN) {   // fused attn dots in fp32 from acc
        float ps[4] = {0.f, 0.f, 0.f, 0.f};
        float pd[4] = {0.f, 0.f, 0.f, 0.f};
#pragma unroll
        for (int c = 0; c < CT; ++c) {
            float sv = a_s[c * 16 + n];
            float dv = a_d[c * 16 + n];
#pragma unroll
            for (int reg = 0; reg < 4; ++reg) {
                ps[reg] = fmaf(acc[c][reg], sv, ps[reg]);
                pd[reg] = fmaf(acc[c][reg], dv, pd[reg]);
            }
        }
#pragma unroll
        for (int off = 1; off < 16; off <<= 1) {
#pragma unroll
            for (int reg = 0; reg < 4; ++reg) {
                ps[reg] += __shfl_xor(ps[reg], off);
                pd[reg] += __shfl_xor(pd[reg], off);
            }
        }
        if (n == 0) {
#pragma unroll
            for (int reg = 0; reg < 4; ++reg) {
                int row = row0 + quad * 4 + reg;
                if (row < M) { asv[row] = ps[reg]; adv[row] = pd[reg]; }
            }
        }
    }
}

// fma 8 halves (one uint4) scaled by al into acc[0..7]
__device__ inline void fma_h8(uint4 u, float al, float* acc) {
    float2 f0 = __half22float2(*(__half2*)&u.x);
    float2 f1 = __half22float2(*(__half2*)&u.y);
    float2 f2 = __half22float2(*(__half2*)&u.z);
    float2 f3 = __half22float2(*(__half2*)&u.w);
    acc[0] = fmaf(al, f0.x, acc[0]);
    acc[1] = fmaf(al, f0.y, acc[1]);
    acc[2] = fmaf(al, f1.x, acc[2]);
    acc[3] = fmaf(al, f1.y, acc[3]);
    acc[4] = fmaf(al, f2.x, acc[4]);
    acc[5] = fmaf(al, f2.y, acc[5]);
    acc[6] = fmaf(al, f3.x, acc[6]);
    acc[7] = fmaf(al, f3.y, acc[7]);
}

// ---------------- GAT aggregation: fp16 gather, fp16 out, 8 edge-slots x 8 lanes ----------------

__global__ __launch_bounds__(256) void k_gat_agg(const __half* __restrict__ h,
                                                 const int* __restrict__ cnt,
                                                 const u16* __restrict__ csr,
                                                 const float* __restrict__ asv,
                                                 const float* __restrict__ adv,
                                                 const float* __restrict__ bias,
                                                 __half* __restrict__ outp) {
    int lane = threadIdx.x & 63, wv = threadIdx.x >> 6;
    int d = blockIdx.x * 4 + wv;
    if (d >= NN) return;
    int deg = cnt[d]; if (deg > CAP) deg = CAP;
    const float advd = adv[d];
    const u16* rowp = csr + (size_t)d * CAP;

    // ---- phase A: exact softmax over <=80 edges in 2 register chunks ----
    int j0 = lane, j1 = lane + 64;
    int s0 = 0, s1 = 0;
    float e0 = -INFINITY, e1 = -INFINITY;
    if (j0 < deg) {
        s0 = rowp[j0];
        float t = asv[s0] + advd;
        e0 = (t >= 0.f) ? t : NEG * t;
    }
    if (j1 < deg) {
        s1 = rowp[j1];
        float t = asv[s1] + advd;
        e1 = (t >= 0.f) ? t : NEG * t;
    }
    float m = fmaxf(e0, e1);
#pragma unroll
    for (int off = 32; off; off >>= 1) m = fmaxf(m, __shfl_xor(m, off));
    float p0 = (j0 < deg) ? __expf(e0 - m) : 0.f;
    float p1 = (j1 < deg) ? __expf(e1 - m) : 0.f;
    float s = p0 + p1;
#pragma unroll
    for (int off = 32; off; off >>= 1) s += __shfl_xor(s, off);
    float inv = 1.f / s;
    float a0 = p0 * inv, a1 = p1 * inv;

    // ---- phase B: 8 edge-slots, lane r owns 16 cols (2 x uint4 of halves) ----
    int slot = lane >> 3, r = lane & 7;
    float acc[16];
#pragma unroll
    for (int k = 0; k < 16; ++k) acc[k] = 0.f;

    for (int base = 0; base < deg; base += 8) {
        int idx = base + slot;
        int lsrc = idx & 63;
        float alA = __shfl(a0, lsrc);
        float alB = __shfl(a1, lsrc);
        int   sjA = __shfl(s0, lsrc);
        int   sjB = __shfl(s1, lsrc);
        bool ok = idx < deg;
        float al = ok ? ((idx < 64) ? alA : alB) : 0.f;
        int   sj = ok ? ((idx < 64) ? sjA : sjB) : 0;
        const uint4* hp = (const uint4*)&h[(size_t)sj * 128 + r * 16];
        uint4 ua = hp[0];
        uint4 ub = hp[1];
        fma_h8(ua, al, acc);
        fma_h8(ub, al, acc + 8);
    }
#pragma unroll
    for (int k = 0; k < 16; ++k) {
        acc[k] += __shfl_xor(acc[k], 8);
        acc[k] += __shfl_xor(acc[k], 16);
        acc[k] += __shfl_xor(acc[k], 32);
    }
    if (slot == 0) {
        __half2 ho[8];
#pragma unroll
        for (int k = 0; k < 8; ++k) {
            float oa = fmaxf(acc[2 * k]     + bias[r * 16 + 2 * k],     0.f);
            float ob = fmaxf(acc[2 * k + 1] + bias[r * 16 + 2 * k + 1], 0.f);
            ho[k] = __floats2half2_rn(oa, ob);
        }
        uint4 u0, u1;
        __builtin_memcpy(&u0, &ho[0], 16);
        __builtin_memcpy(&u1, &ho[4], 16);
        uint4* op = (uint4*)&outp[(size_t)d * 128 + r * 16];
        op[0] = u0; op[1] = u1;
    }
}

// ---------------- GCN aggregation: fp16 gather, fp32 z out ----------------

__global__ __launch_bounds__(256) void k_gcn_agg(const __half* __restrict__ h,
                                                 const int* __restrict__ cnt,
                                                 const u16* __restrict__ csr,
                                                 const float* __restrict__ bias,
                                                 float* __restrict__ z) {
    int lane = threadIdx.x & 63, wv = threadIdx.x >> 6;
    int d = blockIdx.x * 4 + wv;
    if (d >= NN) return;
    int degc = cnt[d];
    int deg = degc > CAP ? CAP : degc;
    float did = rsqrtf((float)degc);
    const u16* rowp = csr + (size_t)d * CAP;

    int j0 = lane, j1 = lane + 64;
    int s0 = 0, s1 = 0;
    float n0 = 0.f, n1 = 0.f;
    if (j0 < deg) { s0 = rowp[j0]; n0 = rsqrtf((float)cnt[s0]) * did; }
    if (j1 < deg) { s1 = rowp[j1]; n1 = rsqrtf((float)cnt[s1]) * did; }

    int slot = lane >> 3, r = lane & 7;
    float acc[8];
#pragma unroll
    for (int k = 0; k < 8; ++k) acc[k] = 0.f;

    for (int base = 0; base < deg; base += 8) {
        int idx = base + slot;
        int lsrc = idx & 63;
        float nA = __shfl(n0, lsrc);
        float nB = __shfl(n1, lsrc);
        int  sjA = __shfl(s0, lsrc);
        int  sjB = __shfl(s1, lsrc);
        bool ok = idx < deg;
        float nm = ok ? ((idx < 64) ? nA : nB) : 0.f;
        int   sj = ok ? ((idx < 64) ? sjA : sjB) : 0;
        uint4 u = *(const uint4*)&h[(size_t)sj * 64 + r * 8];
        fma_h8(u, nm, acc);
    }
#pragma unroll
    for (int k = 0; k < 8; ++k) {
        acc[k] += __shfl_xor(acc[k], 8);
        acc[k] += __shfl_xor(acc[k], 16);
        acc[k] += __shfl_xor(acc[k], 32);
    }
    if (slot == 0) {
        float4 b0 = *(const float4*)&bias[r * 8];
        float4 b1 = *(const float4*)&bias[r * 8 + 4];
        float4* zp = (float4*)&z[(size_t)d * 64 + r * 8];
        zp[0] = make_float4(acc[0] + b0.x, acc[1] + b0.y, acc[2] + b0.z, acc[3] + b0.w);
        zp[1] = make_float4(acc[4] + b1.x, acc[5] + b1.y, acc[6] + b1.z, acc[7] + b1.w);
    }
}

// ---------------- link decode ----------------

__global__ __launch_bounds__(256) void k_decode(const float* __restrict__ z,
                                                const int* __restrict__ eli,
                                                float* __restrict__ outp) {
    int lane = threadIdx.x & 63, wv = threadIdx.x >> 6;
    int g = lane >> 4, r = lane & 15;
    int idx = (blockIdx.x * 4 + wv) * 4 + g;
    if (idx >= NLBL) return;
    int a = eli[idx], b = eli[NLBL + idx];
    float4 za = *(const float4*)&z[(size_t)a * 64 + r * 4];
    float4 zb = *(const float4*)&z[(size_t)b * 64 + r * 4];
    float v = za.x * zb.x + za.y * zb.y + za.z * zb.z + za.w * zb.w;
#pragma unroll
    for (int off = 8; off; off >>= 1) v += __shfl_xor(v, off);
    if (r == 0) outp[idx] = v;
}

// ---------------- launch ----------------

extern "C" void kernel_launch(void* const* d_in, const int* in_sizes, int n_in,
                              void* d_out, int out_size, void* d_ws, size_t ws_size,
                              hipStream_t stream) {
    const float* x   = (const float*)d_in[0];
    const int*   ei  = (const int*)d_in[1];
    const int*   eli = (const int*)d_in[2];
    const float* W1 = (const float*)d_in[3];
    const float* a1s = (const float*)d_in[4];
    const float* a1d = (const float*)d_in[5];
    const float* b1 = (const float*)d_in[6];
    const float* W2 = (const float*)d_in[7];
    const float* a2s = (const float*)d_in[8];
    const float* a2d = (const float*)d_in[9];
    const float* b2 = (const float*)d_in[10];
    const float* W3 = (const float*)d_in[11];
    const float* a3s = (const float*)d_in[12];
    const float* a3d = (const float*)d_in[13];
    const float* b3 = (const float*)d_in[14];
    const float* W4 = (const float*)d_in[15];
    const float* b4 = (const float*)d_in[16];
    float* outp = (float*)d_out;

    char* p = (char*)d_ws;
    auto alloc = [&](size_t bytes) -> char* {
        char* r = p;
        p += (bytes + 255) & ~(size_t)255;
        return r;
    };
    int*    cnt  = (int*)alloc((size_t)NN * 4);
    u16*    csr  = (u16*)alloc((size_t)NN * CAP * 2);
    int*    gcnt = (int*)alloc((size_t)NBK * 4);
    float*  asv  = (float*)alloc((size_t)NN * 4);
    float*  advv = (float*)alloc((size_t)NN * 4);
    __half* x16  = (__half*)alloc((size_t)NN * 128 * 2);
    __half* G    = (__half*)alloc((size_t)NN * 128 * 2);   // fp16 gather table
    __half* Bu1  = (__half*)alloc((size_t)NN * 128 * 2);   // fp16 layer outputs
    __half* Bu2  = (__half*)alloc((size_t)NN * 128 * 2);
    float*  zf   = (float*)alloc((size_t)NN * 64 * 4);     // gcn output (fp32)
    unsigned* bins = (unsigned*)alloc((size_t)NBK * CAPB * 4);

    const int gBin  = (NE + CHK - 1) / CHK;
    const int gCast = (NN * 128 / 4 + 255) / 256;
    const int gGemm = (NN + 63) / 64;
    const int gNode = (NN + 3) / 4;
    const int gDec  = (NLBL + 15) / 16;

    k_zero<<<1, 256, 0, stream>>>(gcnt);
    k_bin<<<gBin, 256, 0, stream>>>(ei, gcnt, bins);
    k_build<<<NBK, 256, 0, stream>>>(bins, gcnt, cnt, csr);
    k_cast<<<gCast, 256, 0, stream>>>(x, x16);

    gemm_mfma<128, true><<<gGemm, 256, 0, stream>>>(x16, W1, G, a1s, a1d, asv, advv, NN);
    k_gat_agg<<<gNode, 256, 0, stream>>>(G, cnt, csr, asv, advv, b1, Bu1);

    gemm_mfma<128, true><<<gGemm, 256, 0, stream>>>(Bu1, W2, G, a2s, a2d, asv, advv, NN);
    k_gat_agg<<<gNode, 256, 0, stream>>>(G, cnt, csr, asv, advv, b2, Bu2);

    gemm_mfma<128, true><<<gGemm, 256, 0, stream>>>(Bu2, W3, G, a3s, a3d, asv, advv, NN);
    k_gat_agg<<<gNode, 256, 0, stream>>>(G, cnt, csr, asv, advv, b3, Bu1);

    gemm_mfma<64, false><<<gGemm, 256, 0, stream>>>(Bu1, W4, G, nullptr, nullptr, nullptr, nullptr, NN);
    k_gcn_agg<<<gNode, 256, 0, stream>>>(G, cnt, csr, b4, zf);

    k_decode<<<gDec, 256, 0, stream>>>(zf, eli, outp);
}

// Round 9
// 430.192 us; speedup vs baseline: 1.8495x; 1.0323x over previous
//
#include <hip/hip_runtime.h>
#include <hip/hip_fp16.h>
#include <math.h>

#define NN   50000
#define NE   1600000
#define DHID 128
#define DOUTC 64
#define NLBL 200000
#define CAP  80          // max in-degree+1; Poisson(32): P(deg>=80) ~ 1e-12/node
#define NEG  0.2f
#define NBK  196         // ceil(50000/256) dst buckets of 256 nodes
#define CAPB 8800        // bucket capacity: Poisson(8163) + 7 sigma
#define CHK  4096        // edges per k_bin block

typedef unsigned short u16;
typedef _Float16 half8 __attribute__((ext_vector_type(8)));
typedef float floatx4 __attribute__((ext_vector_type(4)));

// ---------------- CSR build: binned counting sort ----------------

__global__ __launch_bounds__(256) void k_zero(int* __restrict__ gcnt) {
    int i = threadIdx.x;
    if (i < NBK) gcnt[i] = 0;
}

__global__ __launch_bounds__(256) void k_bin(const int* __restrict__ ei,
                                             int* __restrict__ gcnt,
                                             unsigned* __restrict__ bins) {
    __shared__ int cntL[NBK];
    __shared__ int curL[NBK];
    const int tid = threadIdx.x;
    const int e0 = blockIdx.x * CHK + tid * 16;
    const bool act = (e0 + 15) < NE;

    unsigned pk[16];
    int bb[16];
    if (act) {
#pragma unroll
        for (int g = 0; g < 4; ++g) {
            int4 s4 = *(const int4*)&ei[e0 + g * 4];
            int4 d4 = *(const int4*)&ei[NE + e0 + g * 4];
            int sa[4] = {s4.x, s4.y, s4.z, s4.w};
            int da[4] = {d4.x, d4.y, d4.z, d4.w};
#pragma unroll
            for (int k = 0; k < 4; ++k) {
                int idx = g * 4 + k;
                bb[idx] = da[k] >> 8;
                pk[idx] = (unsigned)sa[k] | ((unsigned)(da[k] & 255) << 16);
            }
        }
    }
    for (int i = tid; i < NBK; i += 256) cntL[i] = 0;
    __syncthreads();
    if (act) {
#pragma unroll
        for (int k = 0; k < 16; ++k) atomicAdd(&cntL[bb[k]], 1);
    }
    __syncthreads();
    for (int i = tid; i < NBK; i += 256) curL[i] = atomicAdd(&gcnt[i], cntL[i]);
    __syncthreads();
    if (act) {
#pragma unroll
        for (int k = 0; k < 16; ++k) {
            int off = atomicAdd(&curL[bb[k]], 1);
            bins[(size_t)bb[k] * CAPB + off] = pk[k];
        }
    }
}

__global__ __launch_bounds__(256) void k_build(const unsigned* __restrict__ bins,
                                               const int* __restrict__ gcnt,
                                               int* __restrict__ cnt,
                                               u16* __restrict__ csr) {
    __shared__ u16 rows[256 * CAP];   // 40 KB
    __shared__ int cur[256];
    const int b = blockIdx.x, tid = threadIdx.x;
    const int d0 = b << 8;
    const int nd = min(256, NN - d0);
    if (tid < nd) { cur[tid] = 1; rows[tid * CAP] = (u16)(d0 + tid); }  // self-loop slot 0
    __syncthreads();
    const int n = gcnt[b];
    for (int i = tid; i < n; i += 256) {
        unsigned v = bins[(size_t)b * CAPB + i];
        int s = v & 0xFFFF, dl = v >> 16;
        int pos = atomicAdd(&cur[dl], 1);
        if (pos < CAP) rows[dl * CAP + pos] = (u16)s;
    }
    __syncthreads();
    const unsigned* rw = (const unsigned*)rows;
    unsigned* cw = (unsigned*)(csr + (size_t)d0 * CAP);
    const int tot = nd * (CAP / 2);
    for (int i = tid; i < tot; i += 256) cw[i] = rw[i];
    if (tid < nd) cnt[d0 + tid] = cur[tid];
}

// ---------------- cast x fp32 -> fp16 ----------------

__global__ __launch_bounds__(256) void k_cast(const float* __restrict__ x,
                                              __half* __restrict__ x16) {
    int i = (blockIdx.x * 256 + threadIdx.x) * 4;
    if (i < NN * 128) {
        float4 v = *(const float4*)&x[i];
        __half2 h0 = __floats2half2_rn(v.x, v.y);
        __half2 h1 = __floats2half2_rn(v.z, v.w);
        uint2 u;
        __builtin_memcpy(&u.x, &h0, 4);
        __builtin_memcpy(&u.y, &h1, 4);
        *(uint2*)&x16[i] = u;
    }
}

// ---------------- W -> fp16 fragment layout (global, built once per call) ----------------
// Wf[(c*4+ks)*64 + lane] = half8 { W[ks*32+quad*8+j][c*16+n] }, n=lane&15, quad=lane>>4.
// Used as the MFMA *A-operand* (lane m=lane&15 -> W column), so D rows are W-cols.

__global__ __launch_bounds__(256) void k_prep_w(const float* __restrict__ W1f,
                                                const float* __restrict__ W2f,
                                                const float* __restrict__ W3f,
                                                const float* __restrict__ W4f,
                                                half8* __restrict__ Wf1,
                                                half8* __restrict__ Wf2,
                                                half8* __restrict__ Wf3,
                                                half8* __restrict__ Wf4) {
    int e = blockIdx.x * 256 + threadIdx.x;
    const float* W;
    half8* Wf;
    int nout, le;
    if (e < 2048)      { W = W1f; Wf = Wf1; nout = 128; le = e; }
    else if (e < 4096) { W = W2f; Wf = Wf2; nout = 128; le = e - 2048; }
    else if (e < 6144) { W = W3f; Wf = Wf3; nout = 128; le = e - 4096; }
    else if (e < 7168) { W = W4f; Wf = Wf4; nout = 64;  le = e - 6144; }
    else return;
    int c = le >> 8, rem = le & 255, ks = rem >> 6, lane = rem & 63;
    int n = lane & 15, quad = lane >> 4;
    int col = c * 16 + n, k0 = ks * 32 + quad * 8;
    half8 v;
#pragma unroll
    for (int j = 0; j < 8; ++j) v[j] = (_Float16)W[(size_t)(k0 + j) * nout + col];
    Wf[le] = v;
}

// ---------------- MFMA fp16 GEMM, LDS-free: C16[M,NOUT] = A16[M,128] @ W ----------------
// mfma(argA=W-frag, argB=A-frag): D[row=quad*4+reg -> w_col][col=lane&15 -> a_row].
// Lane owns 4 consecutive cols (quad*4..+3 per c-tile) of row (row0+t*16+n) -> 8B stores.
// 2 row-tiles per wave amortizes the Wf loads.

template <int NOUT, bool ATTN>
__global__ __launch_bounds__(256) void gemm_mfma(const __half* __restrict__ A16,
                                                 const half8* __restrict__ Wf,
                                                 __half* __restrict__ C16,
                                                 const float* __restrict__ a_s,
                                                 const float* __restrict__ a_d,
                                                 float* __restrict__ asv,
                                                 float* __restrict__ adv, int M) {
    constexpr int CT = NOUT / 16;
    const int tid = threadIdx.x;
    const int wave = tid >> 6, lane = tid & 63;
    const int n = lane & 15, quad = lane >> 4;
    const int row0 = blockIdx.x * 128 + wave * 32;   // 2 row-tiles of 16

    half8 a[2][4];
    half8 zz = {};
#pragma unroll
    for (int t = 0; t < 2; ++t) {
        int row = row0 + t * 16 + n;
        const _Float16* Ap = (const _Float16*)A16 + (size_t)row * 128 + quad * 8;
        bool ok = row < M;
#pragma unroll
        for (int ks = 0; ks < 4; ++ks)
            a[t][ks] = ok ? *(const half8*)(Ap + ks * 32) : zz;
    }

    floatx4 acc[2][CT];
#pragma unroll
    for (int t = 0; t < 2; ++t)
#pragma unroll
        for (int c = 0; c < CT; ++c) acc[t][c] = (floatx4){0.f, 0.f, 0.f, 0.f};

#pragma unroll
    for (int c = 0; c < CT; ++c) {
#pragma unroll
        for (int ks = 0; ks < 4; ++ks) {
            half8 b = Wf[(c * 4 + ks) * 64 + lane];
            acc[0][c] = __builtin_amdgcn_mfma_f32_16x16x32_f16(b, a[0][ks], acc[0][c], 0, 0, 0);
            acc[1][c] = __builtin_amdgcn_mfma_f32_16x16x32_f16(b, a[1][ks], acc[1][c], 0, 0, 0);
        }
    }

#pragma unroll
    for (int t = 0; t < 2; ++t) {
        int row = row0 + t * 16 + n;
        if (row < M) {
#pragma unroll
            for (int c = 0; c < CT; ++c) {
                __half2 h0 = __floats2half2_rn(acc[t][c][0], acc[t][c][1]);
                __half2 h1 = __floats2half2_rn(acc[t][c][2], acc[t][c][3]);
                uint2 u;
                __builtin_memcpy(&u.x, &h0, 4);
                __builtin_memcpy(&u.y, &h1, 4);
                *(uint2*)&C16[(size_t)row * NOUT + c * 16 + quad * 4] = u;
            }
        }
    }

    if (ATTN) {   // fused attn dots (fp32, from acc); reduce across quads
#pragma unroll
        for (int t = 0; t < 2; ++t) {
            float ps = 0.f, pd = 0.f;
#pragma unroll
            for (int c = 0; c < CT; ++c) {
#pragma unroll
                for (int reg = 0; reg < 4; ++reg) {
                    float w = acc[t][c][reg];
                    ps = fmaf(w, a_s[c * 16 + quad * 4 + reg], ps);
                    pd = fmaf(w, a_d[c * 16 + quad * 4 + reg], pd);
                }
            }
            ps += __shfl_xor(ps, 16); ps += __shfl_xor(ps, 32);
            pd += __shfl_xor(pd, 16); pd += __shfl_xor(pd, 32);
            int row = row0 + t * 16 + n;
            if (quad == 0 && row < M) { asv[row] = ps; adv[row] = pd; }
        }
    }
}

// fma 8 halves (one uint4) scaled by al into acc[0..7]
__device__ inline void fma_h8(uint4 u, float al, float* acc) {
    float2 f0 = __half22float2(*(__half2*)&u.x);
    float2 f1 = __half22float2(*(__half2*)&u.y);
    float2 f2 = __half22float2(*(__half2*)&u.z);
    float2 f3 = __half22float2(*(__half2*)&u.w);
    acc[0] = fmaf(al, f0.x, acc[0]);
    acc[1] = fmaf(al, f0.y, acc[1]);
    acc[2] = fmaf(al, f1.x, acc[2]);
    acc[3] = fmaf(al, f1.y, acc[3]);
    acc[4] = fmaf(al, f2.x, acc[4]);
    acc[5] = fmaf(al, f2.y, acc[5]);
    acc[6] = fmaf(al, f3.x, acc[6]);
    acc[7] = fmaf(al, f3.y, acc[7]);
}

// ---------------- GAT aggregation: fp16 gather, fp16 out, 8 edge-slots x 8 lanes ----------------

__global__ __launch_bounds__(256) void k_gat_agg(const __half* __restrict__ h,
                                                 const int* __restrict__ cnt,
                                                 const u16* __restrict__ csr,
                                                 const float* __restrict__ asv,
                                                 const float* __restrict__ adv,
                                                 const float* __restrict__ bias,
                                                 __half* __restrict__ outp) {
    int lane = threadIdx.x & 63, wv = threadIdx.x >> 6;
    int d = blockIdx.x * 4 + wv;
    if (d >= NN) return;
    int deg = cnt[d]; if (deg > CAP) deg = CAP;
    const float advd = adv[d];
    const u16* rowp = csr + (size_t)d * CAP;

    // ---- phase A: exact softmax over <=80 edges in 2 register chunks ----
    int j0 = lane, j1 = lane + 64;
    int s0 = 0, s1 = 0;
    float e0 = -INFINITY, e1 = -INFINITY;
    if (j0 < deg) {
        s0 = rowp[j0];
        float t = asv[s0] + advd;
        e0 = (t >= 0.f) ? t : NEG * t;
    }
    if (j1 < deg) {
        s1 = rowp[j1];
        float t = asv[s1] + advd;
        e1 = (t >= 0.f) ? t : NEG * t;
    }
    float m = fmaxf(e0, e1);
#pragma unroll
    for (int off = 32; off; off >>= 1) m = fmaxf(m, __shfl_xor(m, off));
    float p0 = (j0 < deg) ? __expf(e0 - m) : 0.f;
    float p1 = (j1 < deg) ? __expf(e1 - m) : 0.f;
    float s = p0 + p1;
#pragma unroll
    for (int off = 32; off; off >>= 1) s += __shfl_xor(s, off);
    float inv = 1.f / s;
    float a0 = p0 * inv, a1 = p1 * inv;

    // ---- phase B: 8 edge-slots, lane r owns 16 cols (2 x uint4 of halves) ----
    int slot = lane >> 3, r = lane & 7;
    float acc[16];
#pragma unroll
    for (int k = 0; k < 16; ++k) acc[k] = 0.f;

    for (int base = 0; base < deg; base += 8) {
        int idx = base + slot;
        int lsrc = idx & 63;
        float alA = __shfl(a0, lsrc);
        float alB = __shfl(a1, lsrc);
        int   sjA = __shfl(s0, lsrc);
        int   sjB = __shfl(s1, lsrc);
        bool ok = idx < deg;
        float al = ok ? ((idx < 64) ? alA : alB) : 0.f;
        int   sj = ok ? ((idx < 64) ? sjA : sjB) : 0;
        const uint4* hp = (const uint4*)&h[(size_t)sj * 128 + r * 16];
        uint4 ua = hp[0];
        uint4 ub = hp[1];
        fma_h8(ua, al, acc);
        fma_h8(ub, al, acc + 8);
    }
#pragma unroll
    for (int k = 0; k < 16; ++k) {
        acc[k] += __shfl_xor(acc[k], 8);
        acc[k] += __shfl_xor(acc[k], 16);
        acc[k] += __shfl_xor(acc[k], 32);
    }
    if (slot == 0) {
        __half2 ho[8];
#pragma unroll
        for (int k = 0; k < 8; ++k) {
            float oa = fmaxf(acc[2 * k]     + bias[r * 16 + 2 * k],     0.f);
            float ob = fmaxf(acc[2 * k + 1] + bias[r * 16 + 2 * k + 1], 0.f);
            ho[k] = __floats2half2_rn(oa, ob);
        }
        uint4 u0, u1;
        __builtin_memcpy(&u0, &ho[0], 16);
        __builtin_memcpy(&u1, &ho[4], 16);
        uint4* op = (uint4*)&outp[(size_t)d * 128 + r * 16];
        op[0] = u0; op[1] = u1;
    }
}

// ---------------- GCN aggregation: fp16 gather, fp32 z out ----------------

__global__ __launch_bounds__(256) void k_gcn_agg(const __half* __restrict__ h,
                                                 const int* __restrict__ cnt,
                                                 const u16* __restrict__ csr,
                                                 const float* __restrict__ bias,
                                                 float* __restrict__ z) {
    int lane = threadIdx.x & 63, wv = threadIdx.x >> 6;
    int d = blockIdx.x * 4 + wv;
    if (d >= NN) return;
    int degc = cnt[d];
    int deg = degc > CAP ? CAP : degc;
    float did = rsqrtf((float)degc);
    const u16* rowp = csr + (size_t)d * CAP;

    int j0 = lane, j1 = lane + 64;
    int s0 = 0, s1 = 0;
    float n0 = 0.f, n1 = 0.f;
    if (j0 < deg) { s0 = rowp[j0]; n0 = rsqrtf((float)cnt[s0]) * did; }
    if (j1 < deg) { s1 = rowp[j1]; n1 = rsqrtf((float)cnt[s1]) * did; }

    int slot = lane >> 3, r = lane & 7;
    float acc[8];
#pragma unroll
    for (int k = 0; k < 8; ++k) acc[k] = 0.f;

    for (int base = 0; base < deg; base += 8) {
        int idx = base + slot;
        int lsrc = idx & 63;
        float nA = __shfl(n0, lsrc);
        float nB = __shfl(n1, lsrc);
        int  sjA = __shfl(s0, lsrc);
        int  sjB = __shfl(s1, lsrc);
        bool ok = idx < deg;
        float nm = ok ? ((idx < 64) ? nA : nB) : 0.f;
        int   sj = ok ? ((idx < 64) ? sjA : sjB) : 0;
        uint4 u = *(const uint4*)&h[(size_t)sj * 64 + r * 8];
        fma_h8(u, nm, acc);
    }
#pragma unroll
    for (int k = 0; k < 8; ++k) {
        acc[k] += __shfl_xor(acc[k], 8);
        acc[k] += __shfl_xor(acc[k], 16);
        acc[k] += __shfl_xor(acc[k], 32);
    }
    if (slot == 0) {
        float4 b0 = *(const float4*)&bias[r * 8];
        float4 b1 = *(const float4*)&bias[r * 8 + 4];
        float4* zp = (float4*)&z[(size_t)d * 64 + r * 8];
        zp[0] = make_float4(acc[0] + b0.x, acc[1] + b0.y, acc[2] + b0.z, acc[3] + b0.w);
        zp[1] = make_float4(acc[4] + b1.x, acc[5] + b1.y, acc[6] + b1.z, acc[7] + b1.w);
    }
}

// ---------------- link decode ----------------

__global__ __launch_bounds__(256) void k_decode(const float* __restrict__ z,
                                                const int* __restrict__ eli,
                                                float* __restrict__ outp) {
    int lane = threadIdx.x & 63, wv = threadIdx.x >> 6;
    int g = lane >> 4, r = lane & 15;
    int idx = (blockIdx.x * 4 + wv) * 4 + g;
    if (idx >= NLBL) return;
    int a = eli[idx], b = eli[NLBL + idx];
    float4 za = *(const float4*)&z[(size_t)a * 64 + r * 4];
    float4 zb = *(const float4*)&z[(size_t)b * 64 + r * 4];
    float v = za.x * zb.x + za.y * zb.y + za.z * zb.z + za.w * zb.w;
#pragma unroll
    for (int off = 8; off; off >>= 1) v += __shfl_xor(v, off);
    if (r == 0) outp[idx] = v;
}

// ---------------- launch ----------------

extern "C" void kernel_launch(void* const* d_in, const int* in_sizes, int n_in,
                              void* d_out, int out_size, void* d_ws, size_t ws_size,
                              hipStream_t stream) {
    const float* x   = (const float*)d_in[0];
    const int*   ei  = (const int*)d_in[1];
    const int*   eli = (const int*)d_in[2];
    const float* W1 = (const float*)d_in[3];
    const float* a1s = (const float*)d_in[4];
    const float* a1d = (const float*)d_in[5];
    const float* b1 = (const float*)d_in[6];
    const float* W2 = (const float*)d_in[7];
    const float* a2s = (const float*)d_in[8];
    const float* a2d = (const float*)d_in[9];
    const float* b2 = (const float*)d_in[10];
    const float* W3 = (const float*)d_in[11];
    const float* a3s = (const float*)d_in[12];
    const float* a3d = (const float*)d_in[13];
    const float* b3 = (const float*)d_in[14];
    const float* W4 = (const float*)d_in[15];
    const float* b4 = (const float*)d_in[16];
    float* outp = (float*)d_out;

    char* p = (char*)d_ws;
    auto alloc = [&](size_t bytes) -> char* {
        char* r = p;
        p += (bytes + 255) & ~(size_t)255;
        return r;
    };
    int*    cnt  = (int*)alloc((size_t)NN * 4);
    u16*    csr  = (u16*)alloc((size_t)NN * CAP * 2);
    int*    gcnt = (int*)alloc((size_t)NBK * 4);
    float*  asv  = (float*)alloc((size_t)NN * 4);
    float*  advv = (float*)alloc((size_t)NN * 4);
    __half* x16  = (__half*)alloc((size_t)NN * 128 * 2);
    __half* G    = (__half*)alloc((size_t)NN * 128 * 2);   // fp16 gather table
    __half* Bu1  = (__half*)alloc((size_t)NN * 128 * 2);   // fp16 layer outputs
    __half* Bu2  = (__half*)alloc((size_t)NN * 128 * 2);
    float*  zf   = (float*)alloc((size_t)NN * 64 * 4);     // gcn output (fp32)
    half8*  Wf1  = (half8*)alloc(2048 * 16);
    half8*  Wf2  = (half8*)alloc(2048 * 16);
    half8*  Wf3  = (half8*)alloc(2048 * 16);
    half8*  Wf4  = (half8*)alloc(1024 * 16);
    unsigned* bins = (unsigned*)alloc((size_t)NBK * CAPB * 4);

    const int gBin  = (NE + CHK - 1) / CHK;
    const int gCast = (NN * 128 / 4 + 255) / 256;
    const int gGemm = (NN + 127) / 128;
    const int gNode = (NN + 3) / 4;
    const int gDec  = (NLBL + 15) / 16;

    k_zero<<<1, 256, 0, stream>>>(gcnt);
    k_bin<<<gBin, 256, 0, stream>>>(ei, gcnt, bins);
    k_build<<<NBK, 256, 0, stream>>>(bins, gcnt, cnt, csr);
    k_cast<<<gCast, 256, 0, stream>>>(x, x16);
    k_prep_w<<<28, 256, 0, stream>>>(W1, W2, W3, W4, Wf1, Wf2, Wf3, Wf4);

    gemm_mfma<128, true><<<gGemm, 256, 0, stream>>>(x16, Wf1, G, a1s, a1d, asv, advv, NN);
    k_gat_agg<<<gNode, 256, 0, stream>>>(G, cnt, csr, asv, advv, b1, Bu1);

    gemm_mfma<128, true><<<gGemm, 256, 0, stream>>>(Bu1, Wf2, G, a2s, a2d, asv, advv, NN);
    k_gat_agg<<<gNode, 256, 0, stream>>>(G, cnt, csr, asv, advv, b2, Bu2);

    gemm_mfma<128, true><<<gGemm, 256, 0, stream>>>(Bu2, Wf3, G, a3s, a3d, asv, advv, NN);
    k_gat_agg<<<gNode, 256, 0, stream>>>(G, cnt, csr, asv, advv, b3, Bu1);

    gemm_mfma<64, false><<<gGemm, 256, 0, stream>>>(Bu1, Wf4, G, nullptr, nullptr, nullptr, nullptr, NN);
    k_gcn_agg<<<gNode, 256, 0, stream>>>(G, cnt, csr, b4, zf);

    k_decode<<<gDec, 256, 0, stream>>>(zf, eli, outp);
}

// Round 10
// 398.720 us; speedup vs baseline: 1.9955x; 1.0789x over previous
//
#include <hip/hip_runtime.h>
#include <hip/hip_fp16.h>
#include <math.h>

#define NN   50000
#define NE   1600000
#define DHID 128
#define DOUTC 64
#define NLBL 200000
#define CAP  80          // max in-degree+1; Poisson(32): P(deg>=80) ~ 1e-12/node
#define NEG  0.2f
#define NBK  196         // ceil(50000/256) dst buckets of 256 nodes
#define CAPB 8800        // bucket capacity: Poisson(8163) + 7 sigma
#define CHK  4096        // edges per k_bin block

typedef unsigned short u16;
typedef _Float16 half8 __attribute__((ext_vector_type(8)));
typedef float floatx4 __attribute__((ext_vector_type(4)));

// ---------------- CSR build: binned counting sort ----------------

__global__ __launch_bounds__(256) void k_bin(const int* __restrict__ ei,
                                             int* __restrict__ gcnt,
                                             unsigned* __restrict__ bins) {
    __shared__ int cntL[NBK];
    __shared__ int curL[NBK];
    const int tid = threadIdx.x;
    const int e0 = blockIdx.x * CHK + tid * 16;
    const bool act = (e0 + 15) < NE;

    unsigned pk[16];
    int bb[16];
    if (act) {
#pragma unroll
        for (int g = 0; g < 4; ++g) {
            int4 s4 = *(const int4*)&ei[e0 + g * 4];
            int4 d4 = *(const int4*)&ei[NE + e0 + g * 4];
            int sa[4] = {s4.x, s4.y, s4.z, s4.w};
            int da[4] = {d4.x, d4.y, d4.z, d4.w};
#pragma unroll
            for (int k = 0; k < 4; ++k) {
                int idx = g * 4 + k;
                bb[idx] = da[k] >> 8;
                pk[idx] = (unsigned)sa[k] | ((unsigned)(da[k] & 255) << 16);
            }
        }
    }
    for (int i = tid; i < NBK; i += 256) cntL[i] = 0;
    __syncthreads();
    if (act) {
#pragma unroll
        for (int k = 0; k < 16; ++k) atomicAdd(&cntL[bb[k]], 1);
    }
    __syncthreads();
    for (int i = tid; i < NBK; i += 256) curL[i] = atomicAdd(&gcnt[i], cntL[i]);
    __syncthreads();
    if (act) {
#pragma unroll
        for (int k = 0; k < 16; ++k) {
            int off = atomicAdd(&curL[bb[k]], 1);
            bins[(size_t)bb[k] * CAPB + off] = pk[k];
        }
    }
}

__global__ __launch_bounds__(256) void k_build(const unsigned* __restrict__ bins,
                                               const int* __restrict__ gcnt,
                                               int* __restrict__ cnt,
                                               u16* __restrict__ csr) {
    __shared__ u16 rows[256 * CAP];   // 40 KB
    __shared__ int cur[256];
    const int b = blockIdx.x, tid = threadIdx.x;
    const int d0 = b << 8;
    const int nd = min(256, NN - d0);
    if (tid < nd) { cur[tid] = 1; rows[tid * CAP] = (u16)(d0 + tid); }  // self-loop slot 0
    __syncthreads();
    const int n = gcnt[b];
    for (int i = tid; i < n; i += 256) {
        unsigned v = bins[(size_t)b * CAPB + i];
        int s = v & 0xFFFF, dl = v >> 16;
        int pos = atomicAdd(&cur[dl], 1);
        if (pos < CAP) rows[dl * CAP + pos] = (u16)s;
    }
    __syncthreads();
    const unsigned* rw = (const unsigned*)rows;
    unsigned* cw = (unsigned*)(csr + (size_t)d0 * CAP);
    const int tot = nd * (CAP / 2);
    for (int i = tid; i < tot; i += 256) cw[i] = rw[i];
    if (tid < nd) cnt[d0 + tid] = cur[tid];
}

// ---------------- W -> fp16 fragment layout + gcnt zero (one kernel) ----------------
// Wf[(c*4+ks)*64 + lane] = half8 { W[ks*32+quad*8+j][c*16+n] }, n=lane&15, quad=lane>>4.

__global__ __launch_bounds__(256) void k_prep_w(const float* __restrict__ W1f,
                                                const float* __restrict__ W2f,
                                                const float* __restrict__ W3f,
                                                const float* __restrict__ W4f,
                                                half8* __restrict__ Wf1,
                                                half8* __restrict__ Wf2,
                                                half8* __restrict__ Wf3,
                                                half8* __restrict__ Wf4,
                                                int* __restrict__ gcnt) {
    if (blockIdx.x == 28) {       // folded k_zero
        int i = threadIdx.x;
        if (i < NBK) gcnt[i] = 0;
        return;
    }
    int e = blockIdx.x * 256 + threadIdx.x;
    const float* W;
    half8* Wf;
    int nout, le;
    if (e < 2048)      { W = W1f; Wf = Wf1; nout = 128; le = e; }
    else if (e < 4096) { W = W2f; Wf = Wf2; nout = 128; le = e - 2048; }
    else if (e < 6144) { W = W3f; Wf = Wf3; nout = 128; le = e - 4096; }
    else               { W = W4f; Wf = Wf4; nout = 64;  le = e - 6144; }
    int c = le >> 8, rem = le & 255, ks = rem >> 6, lane = rem & 63;
    int n = lane & 15, quad = lane >> 4;
    int col = c * 16 + n, k0 = ks * 32 + quad * 8;
    half8 v;
#pragma unroll
    for (int j = 0; j < 8; ++j) v[j] = (_Float16)W[(size_t)(k0 + j) * nout + col];
    Wf[le] = v;
}

// ---------------- MFMA fp16 GEMM, LDS-free ----------------
// mfma(argA=W-frag, argB=A-frag): D[row=quad*4+reg -> w_col][col=lane&15 -> a_row].
// 64 rows/block (1 row-tile/wave) for load balance: 782 blocks.

template <int NOUT, bool ATTN, typename TA>
__global__ __launch_bounds__(256) void gemm_mfma(const TA* __restrict__ Ain,
                                                 const half8* __restrict__ Wf,
                                                 __half* __restrict__ C16,
                                                 const float* __restrict__ a_s,
                                                 const float* __restrict__ a_d,
                                                 float* __restrict__ asv,
                                                 float* __restrict__ adv, int M) {
    constexpr int CT = NOUT / 16;
    const int tid = threadIdx.x;
    const int wave = tid >> 6, lane = tid & 63;
    const int n = lane & 15, quad = lane >> 4;
    const int row0 = blockIdx.x * 64 + wave * 16;

    const int row = row0 + n;
    const bool ok = row < M;
    half8 a[4];
    half8 zz = {};
#pragma unroll
    for (int ks = 0; ks < 4; ++ks) {
        if (!ok) { a[ks] = zz; continue; }
        if constexpr (sizeof(TA) == 2) {
            a[ks] = *(const half8*)((const _Float16*)Ain + (size_t)row * 128 + quad * 8 + ks * 32);
        } else {
            const float* Ap = (const float*)Ain + (size_t)row * 128 + quad * 8 + ks * 32;
            float4 f0 = *(const float4*)Ap;
            float4 f1 = *(const float4*)(Ap + 4);
            half8 v;
            v[0] = (_Float16)f0.x; v[1] = (_Float16)f0.y; v[2] = (_Float16)f0.z; v[3] = (_Float16)f0.w;
            v[4] = (_Float16)f1.x; v[5] = (_Float16)f1.y; v[6] = (_Float16)f1.z; v[7] = (_Float16)f1.w;
            a[ks] = v;
        }
    }

    floatx4 acc[CT];
#pragma unroll
    for (int c = 0; c < CT; ++c) acc[c] = (floatx4){0.f, 0.f, 0.f, 0.f};

#pragma unroll
    for (int c = 0; c < CT; ++c) {
#pragma unroll
        for (int ks = 0; ks < 4; ++ks) {
            half8 b = Wf[(c * 4 + ks) * 64 + lane];
            acc[c] = __builtin_amdgcn_mfma_f32_16x16x32_f16(b, a[ks], acc[c], 0, 0, 0);
        }
    }

    if (ok) {
#pragma unroll
        for (int c = 0; c < CT; ++c) {
            __half2 h0 = __floats2half2_rn(acc[c][0], acc[c][1]);
            __half2 h1 = __floats2half2_rn(acc[c][2], acc[c][3]);
            uint2 u;
            __builtin_memcpy(&u.x, &h0, 4);
            __builtin_memcpy(&u.y, &h1, 4);
            *(uint2*)&C16[(size_t)row * NOUT + c * 16 + quad * 4] = u;
        }
    }

    if (ATTN) {   // fused attn dots (fp32 from acc); reduce across quads
        float ps = 0.f, pd = 0.f;
#pragma unroll
        for (int c = 0; c < CT; ++c) {
#pragma unroll
            for (int reg = 0; reg < 4; ++reg) {
                float w = acc[c][reg];
                ps = fmaf(w, a_s[c * 16 + quad * 4 + reg], ps);
                pd = fmaf(w, a_d[c * 16 + quad * 4 + reg], pd);
            }
        }
        ps += __shfl_xor(ps, 16); ps += __shfl_xor(ps, 32);
        pd += __shfl_xor(pd, 16); pd += __shfl_xor(pd, 32);
        if (quad == 0 && ok) { asv[row] = ps; adv[row] = pd; }
    }
}

// fma 8 halves (one uint4) scaled by al into acc[0..7]
__device__ inline void fma_h8(uint4 u, float al, float* acc) {
    float2 f0 = __half22float2(*(__half2*)&u.x);
    float2 f1 = __half22float2(*(__half2*)&u.y);
    float2 f2 = __half22float2(*(__half2*)&u.z);
    float2 f3 = __half22float2(*(__half2*)&u.w);
    acc[0] = fmaf(al, f0.x, acc[0]);
    acc[1] = fmaf(al, f0.y, acc[1]);
    acc[2] = fmaf(al, f1.x, acc[2]);
    acc[3] = fmaf(al, f1.y, acc[3]);
    acc[4] = fmaf(al, f2.x, acc[4]);
    acc[5] = fmaf(al, f2.y, acc[5]);
    acc[6] = fmaf(al, f3.x, acc[6]);
    acc[7] = fmaf(al, f3.y, acc[7]);
}

// ---------------- GAT aggregation: LDS alpha/src handoff, branchless padded loop ----------------

__global__ __launch_bounds__(256) void k_gat_agg(const __half* __restrict__ h,
                                                 const int* __restrict__ cnt,
                                                 const u16* __restrict__ csr,
                                                 const float* __restrict__ asv,
                                                 const float* __restrict__ adv,
                                                 const float* __restrict__ bias,
                                                 __half* __restrict__ outp) {
    __shared__ float alsL[4][88];
    __shared__ int   srcL[4][88];
    int lane = threadIdx.x & 63, wv = threadIdx.x >> 6;
    int d = blockIdx.x * 4 + wv;
    if (d >= NN) return;
    int deg = cnt[d]; if (deg > CAP) deg = CAP;
    const float advd = adv[d];
    const u16* rowp = csr + (size_t)d * CAP;

    // ---- phase A: exact softmax over <=80 edges in 2 register chunks ----
    int j0 = lane, j1 = lane + 64;
    int s0 = 0, s1 = 0;
    float e0 = -INFINITY, e1 = -INFINITY;
    if (j0 < deg) {
        s0 = rowp[j0];
        float t = asv[s0] + advd;
        e0 = (t >= 0.f) ? t : NEG * t;
    }
    if (j1 < deg) {
        s1 = rowp[j1];
        float t = asv[s1] + advd;
        e1 = (t >= 0.f) ? t : NEG * t;
    }
    float m = fmaxf(e0, e1);
#pragma unroll
    for (int off = 32; off; off >>= 1) m = fmaxf(m, __shfl_xor(m, off));
    float p0 = (j0 < deg) ? __expf(e0 - m) : 0.f;
    float p1 = (j1 < deg) ? __expf(e1 - m) : 0.f;
    float s = p0 + p1;
#pragma unroll
    for (int off = 32; off; off >>= 1) s += __shfl_xor(s, off);
    float inv = 1.f / s;
    // write alpha + src to LDS (zero-padded: invalid j has p=0, s=0)
    alsL[wv][j0] = p0 * inv;
    srcL[wv][j0] = s0;
    if (j1 < 88) { alsL[wv][j1] = p1 * inv; srcL[wv][j1] = s1; }

    // ---- phase B: 8 edge-slots x 8 lanes; LDS broadcast, no bounds checks ----
    int slot = lane >> 3, r = lane & 7;
    float acc[16];
#pragma unroll
    for (int k = 0; k < 16; ++k) acc[k] = 0.f;

    int degp = (deg + 7) & ~7;
    for (int base = 0; base < degp; base += 8) {
        int idx = base + slot;
        float al = alsL[wv][idx];
        int   sj = srcL[wv][idx];
        const uint4* hp = (const uint4*)&h[(size_t)sj * 128 + r * 16];
        uint4 ua = hp[0];
        uint4 ub = hp[1];
        fma_h8(ua, al, acc);
        fma_h8(ub, al, acc + 8);
    }
#pragma unroll
    for (int k = 0; k < 16; ++k) {
        acc[k] += __shfl_xor(acc[k], 8);
        acc[k] += __shfl_xor(acc[k], 16);
        acc[k] += __shfl_xor(acc[k], 32);
    }
    if (slot == 0) {
        __half2 ho[8];
#pragma unroll
        for (int k = 0; k < 8; ++k) {
            float oa = fmaxf(acc[2 * k]     + bias[r * 16 + 2 * k],     0.f);
            float ob = fmaxf(acc[2 * k + 1] + bias[r * 16 + 2 * k + 1], 0.f);
            ho[k] = __floats2half2_rn(oa, ob);
        }
        uint4 u0, u1;
        __builtin_memcpy(&u0, &ho[0], 16);
        __builtin_memcpy(&u1, &ho[4], 16);
        uint4* op = (uint4*)&outp[(size_t)d * 128 + r * 16];
        op[0] = u0; op[1] = u1;
    }
}

// ---------------- GCN aggregation: LDS handoff, fp16 z out ----------------

__global__ __launch_bounds__(256) void k_gcn_agg(const __half* __restrict__ h,
                                                 const int* __restrict__ cnt,
                                                 const u16* __restrict__ csr,
                                                 const float* __restrict__ bias,
                                                 __half* __restrict__ z) {
    __shared__ float nmL[4][88];
    __shared__ int   srcL[4][88];
    int lane = threadIdx.x & 63, wv = threadIdx.x >> 6;
    int d = blockIdx.x * 4 + wv;
    if (d >= NN) return;
    int degc = cnt[d];
    int deg = degc > CAP ? CAP : degc;
    float did = rsqrtf((float)degc);
    const u16* rowp = csr + (size_t)d * CAP;

    int j0 = lane, j1 = lane + 64;
    int s0 = 0, s1 = 0;
    float n0 = 0.f, n1 = 0.f;
    if (j0 < deg) { s0 = rowp[j0]; n0 = rsqrtf((float)cnt[s0]) * did; }
    if (j1 < deg) { s1 = rowp[j1]; n1 = rsqrtf((float)cnt[s1]) * did; }
    nmL[wv][j0] = n0;
    srcL[wv][j0] = s0;
    if (j1 < 88) { nmL[wv][j1] = n1; srcL[wv][j1] = s1; }

    int slot = lane >> 3, r = lane & 7;
    float acc[8];
#pragma unroll
    for (int k = 0; k < 8; ++k) acc[k] = 0.f;

    int degp = (deg + 7) & ~7;
    for (int base = 0; base < degp; base += 8) {
        int idx = base + slot;
        float nm = nmL[wv][idx];
        int   sj = srcL[wv][idx];
        uint4 u = *(const uint4*)&h[(size_t)sj * 64 + r * 8];
        fma_h8(u, nm, acc);
    }
#pragma unroll
    for (int k = 0; k < 8; ++k) {
        acc[k] += __shfl_xor(acc[k], 8);
        acc[k] += __shfl_xor(acc[k], 16);
        acc[k] += __shfl_xor(acc[k], 32);
    }
    if (slot == 0) {
        __half2 ho[4];
#pragma unroll
        for (int k = 0; k < 4; ++k) {
            float oa = acc[2 * k]     + bias[r * 8 + 2 * k];
            float ob = acc[2 * k + 1] + bias[r * 8 + 2 * k + 1];
            ho[k] = __floats2half2_rn(oa, ob);
        }
        uint2 u0, u1;
        __builtin_memcpy(&u0, &ho[0], 8);
        __builtin_memcpy(&u1, &ho[2], 8);
        uint2* zp = (uint2*)&z[(size_t)d * 64 + r * 8];
        zp[0] = u0; zp[1] = u1;
    }
}

// ---------------- link decode (fp16 z, fp32 dot) ----------------

__global__ __launch_bounds__(256) void k_decode(const __half* __restrict__ z,
                                                const int* __restrict__ eli,
                                                float* __restrict__ outp) {
    int lane = threadIdx.x & 63, wv = threadIdx.x >> 6;
    int g = lane >> 4, r = lane & 15;
    int idx = (blockIdx.x * 4 + wv) * 4 + g;
    if (idx >= NLBL) return;
    int a = eli[idx], b = eli[NLBL + idx];
    uint2 ua = *(const uint2*)&z[(size_t)a * 64 + r * 4];
    uint2 ub = *(const uint2*)&z[(size_t)b * 64 + r * 4];
    float2 a0 = __half22float2(*(__half2*)&ua.x);
    float2 a1 = __half22float2(*(__half2*)&ua.y);
    float2 b0 = __half22float2(*(__half2*)&ub.x);
    float2 b1 = __half22float2(*(__half2*)&ub.y);
    float v = a0.x * b0.x + a0.y * b0.y + a1.x * b1.x + a1.y * b1.y;
#pragma unroll
    for (int off = 8; off; off >>= 1) v += __shfl_xor(v, off);
    if (r == 0) outp[idx] = v;
}

// ---------------- launch ----------------

extern "C" void kernel_launch(void* const* d_in, const int* in_sizes, int n_in,
                              void* d_out, int out_size, void* d_ws, size_t ws_size,
                              hipStream_t stream) {
    const float* x   = (const float*)d_in[0];
    const int*   ei  = (const int*)d_in[1];
    const int*   eli = (const int*)d_in[2];
    const float* W1 = (const float*)d_in[3];
    const float* a1s = (const float*)d_in[4];
    const float* a1d = (const float*)d_in[5];
    const float* b1 = (const float*)d_in[6];
    const float* W2 = (const float*)d_in[7];
    const float* a2s = (const float*)d_in[8];
    const float* a2d = (const float*)d_in[9];
    const float* b2 = (const float*)d_in[10];
    const float* W3 = (const float*)d_in[11];
    const float* a3s = (const float*)d_in[12];
    const float* a3d = (const float*)d_in[13];
    const float* b3 = (const float*)d_in[14];
    const float* W4 = (const float*)d_in[15];
    const float* b4 = (const float*)d_in[16];
    float* outp = (float*)d_out;

    char* p = (char*)d_ws;
    auto alloc = [&](size_t bytes) -> char* {
        char* r = p;
        p += (bytes + 255) & ~(size_t)255;
        return r;
    };
    int*    cnt  = (int*)alloc((size_t)NN * 4);
    u16*    csr  = (u16*)alloc((size_t)NN * CAP * 2);
    int*    gcnt = (int*)alloc((size_t)NBK * 4);
    float*  asv  = (float*)alloc((size_t)NN * 4);
    float*  advv = (float*)alloc((size_t)NN * 4);
    __half* G    = (__half*)alloc((size_t)NN * 128 * 2);   // fp16 gather table
    __half* Bu1  = (__half*)alloc((size_t)NN * 128 * 2);   // fp16 layer outputs
    __half* Bu2  = (__half*)alloc((size_t)NN * 128 * 2);
    __half* zf   = (__half*)alloc((size_t)NN * 64 * 2);    // gcn output (fp16)
    half8*  Wf1  = (half8*)alloc(2048 * 16);
    half8*  Wf2  = (half8*)alloc(2048 * 16);
    half8*  Wf3  = (half8*)alloc(2048 * 16);
    half8*  Wf4  = (half8*)alloc(1024 * 16);
    unsigned* bins = (unsigned*)alloc((size_t)NBK * CAPB * 4);

    const int gBin  = (NE + CHK - 1) / CHK;
    const int gGemm = (NN + 63) / 64;
    const int gNode = (NN + 3) / 4;
    const int gDec  = (NLBL + 15) / 16;

    k_prep_w<<<29, 256, 0, stream>>>(W1, W2, W3, W4, Wf1, Wf2, Wf3, Wf4, gcnt);
    k_bin<<<gBin, 256, 0, stream>>>(ei, gcnt, bins);
    k_build<<<NBK, 256, 0, stream>>>(bins, gcnt, cnt, csr);

    gemm_mfma<128, true, float><<<gGemm, 256, 0, stream>>>(x, Wf1, G, a1s, a1d, asv, advv, NN);
    k_gat_agg<<<gNode, 256, 0, stream>>>(G, cnt, csr, asv, advv, b1, Bu1);

    gemm_mfma<128, true, __half><<<gGemm, 256, 0, stream>>>(Bu1, Wf2, G, a2s, a2d, asv, advv, NN);
    k_gat_agg<<<gNode, 256, 0, stream>>>(G, cnt, csr, asv, advv, b2, Bu2);

    gemm_mfma<128, true, __half><<<gGemm, 256, 0, stream>>>(Bu2, Wf3, G, a3s, a3d, asv, advv, NN);
    k_gat_agg<<<gNode, 256, 0, stream>>>(G, cnt, csr, asv, advv, b3, Bu1);

    gemm_mfma<64, false, __half><<<gGemm, 256, 0, stream>>>(Bu1, Wf4, G, nullptr, nullptr, nullptr, nullptr, NN);
    k_gcn_agg<<<gNode, 256, 0, stream>>>(G, cnt, csr, b4, zf);

    k_decode<<<gDec, 256, 0, stream>>>(zf, eli, outp);
}

// Round 11
// 388.149 us; speedup vs baseline: 2.0499x; 1.0272x over previous
//
#include <hip/hip_runtime.h>
#include <hip/hip_fp16.h>
#include <math.h>

#define NN   50000
#define NE   1600000
#define DHID 128
#define DOUTC 64
#define NLBL 200000
#define CAP  80          // max in-degree+1; Poisson(32): P(deg>=80) ~ 1e-12/node
#define NEG  0.2f
#define NBK  196         // ceil(50000/256) dst buckets of 256 nodes
#define CAPB 8800        // bucket capacity: Poisson(8163) + 7 sigma
#define CHK  4096        // edges per k_bin block

typedef unsigned short u16;
typedef _Float16 half8 __attribute__((ext_vector_type(8)));
typedef float floatx4 __attribute__((ext_vector_type(4)));

// ---------------- CSR build: binned counting sort ----------------

__global__ __launch_bounds__(256) void k_bin(const int* __restrict__ ei,
                                             int* __restrict__ gcnt,
                                             unsigned* __restrict__ bins) {
    __shared__ int cntL[NBK];
    __shared__ int curL[NBK];
    const int tid = threadIdx.x;
    const int e0 = blockIdx.x * CHK + tid * 16;
    const bool act = (e0 + 15) < NE;

    unsigned pk[16];
    int bb[16];
    if (act) {
#pragma unroll
        for (int g = 0; g < 4; ++g) {
            int4 s4 = *(const int4*)&ei[e0 + g * 4];
            int4 d4 = *(const int4*)&ei[NE + e0 + g * 4];
            int sa[4] = {s4.x, s4.y, s4.z, s4.w};
            int da[4] = {d4.x, d4.y, d4.z, d4.w};
#pragma unroll
            for (int k = 0; k < 4; ++k) {
                int idx = g * 4 + k;
                bb[idx] = da[k] >> 8;
                pk[idx] = (unsigned)sa[k] | ((unsigned)(da[k] & 255) << 16);
            }
        }
    }
    for (int i = tid; i < NBK; i += 256) cntL[i] = 0;
    __syncthreads();
    if (act) {
#pragma unroll
        for (int k = 0; k < 16; ++k) atomicAdd(&cntL[bb[k]], 1);
    }
    __syncthreads();
    for (int i = tid; i < NBK; i += 256) curL[i] = atomicAdd(&gcnt[i], cntL[i]);
    __syncthreads();
    if (act) {
#pragma unroll
        for (int k = 0; k < 16; ++k) {
            int off = atomicAdd(&curL[bb[k]], 1);
            bins[(size_t)bb[k] * CAPB + off] = pk[k];
        }
    }
}

__global__ __launch_bounds__(256) void k_build(const unsigned* __restrict__ bins,
                                               const int* __restrict__ gcnt,
                                               int* __restrict__ cnt,
                                               u16* __restrict__ csr) {
    __shared__ u16 rows[256 * CAP];   // 40 KB
    __shared__ int cur[256];
    const int b = blockIdx.x, tid = threadIdx.x;
    const int d0 = b << 8;
    const int nd = min(256, NN - d0);
    if (tid < nd) { cur[tid] = 1; rows[tid * CAP] = (u16)(d0 + tid); }  // self-loop slot 0
    __syncthreads();
    const int n = gcnt[b];
    for (int i = tid; i < n; i += 256) {
        unsigned v = bins[(size_t)b * CAPB + i];
        int s = v & 0xFFFF, dl = v >> 16;
        int pos = atomicAdd(&cur[dl], 1);
        if (pos < CAP) rows[dl * CAP + pos] = (u16)s;
    }
    __syncthreads();
    const unsigned* rw = (const unsigned*)rows;
    unsigned* cw = (unsigned*)(csr + (size_t)d0 * CAP);
    const int tot = nd * (CAP / 2);
    for (int i = tid; i < tot; i += 256) cw[i] = rw[i];
    if (tid < nd) cnt[d0 + tid] = cur[tid];
}

// ---------------- W -> fp16 fragment layout + gcnt zero ----------------
// Wf[(c*4+ks)*64 + lane] = half8 { W[ks*32+quad*8+j][c*16+n] }, n=lane&15, quad=lane>>4.

__global__ __launch_bounds__(256) void k_prep_w(const float* __restrict__ W1f,
                                                const float* __restrict__ W2f,
                                                const float* __restrict__ W3f,
                                                const float* __restrict__ W4f,
                                                half8* __restrict__ Wf1,
                                                half8* __restrict__ Wf2,
                                                half8* __restrict__ Wf3,
                                                half8* __restrict__ Wf4,
                                                int* __restrict__ gcnt) {
    if (blockIdx.x == 28) {       // folded k_zero
        int i = threadIdx.x;
        if (i < NBK) gcnt[i] = 0;
        return;
    }
    int e = blockIdx.x * 256 + threadIdx.x;
    const float* W;
    half8* Wf;
    int nout, le;
    if (e < 2048)      { W = W1f; Wf = Wf1; nout = 128; le = e; }
    else if (e < 4096) { W = W2f; Wf = Wf2; nout = 128; le = e - 2048; }
    else if (e < 6144) { W = W3f; Wf = Wf3; nout = 128; le = e - 4096; }
    else               { W = W4f; Wf = Wf4; nout = 64;  le = e - 6144; }
    int c = le >> 8, rem = le & 255, ks = rem >> 6, lane = rem & 63;
    int n = lane & 15, quad = lane >> 4;
    int col = c * 16 + n, k0 = ks * 32 + quad * 8;
    half8 v;
#pragma unroll
    for (int j = 0; j < 8; ++j) v[j] = (_Float16)W[(size_t)(k0 + j) * nout + col];
    Wf[le] = v;
}

// ---------------- MFMA fp16 GEMM, LDS-free, split-column output ----------------
// mfma(argA=W-frag, argB=A-frag): D[row=quad*4+reg -> w_col][col=lane&15 -> a_row].
// NOUT=128: cols 0-63 -> C0[row*64+..], 64-127 -> C1. NOUT=64: C0 only.
// A-input: fp32 contiguous (layer 1) or split fp16 pair A0/A1.

template <int NOUT, bool ATTN, typename TA>
__global__ __launch_bounds__(256) void gemm_mfma(const TA* __restrict__ A0,
                                                 const TA* __restrict__ A1,
                                                 const half8* __restrict__ Wf,
                                                 __half* __restrict__ C0,
                                                 __half* __restrict__ C1,
                                                 const float* __restrict__ a_s,
                                                 const float* __restrict__ a_d,
                                                 float* __restrict__ asv,
                                                 float* __restrict__ adv, int M) {
    constexpr int CT = NOUT / 16;
    const int tid = threadIdx.x;
    const int wave = tid >> 6, lane = tid & 63;
    const int n = lane & 15, quad = lane >> 4;
    const int row0 = blockIdx.x * 64 + wave * 16;

    const int row = row0 + n;
    const bool ok = row < M;
    half8 a[4];
    half8 zz = {};
#pragma unroll
    for (int ks = 0; ks < 4; ++ks) {
        if (!ok) { a[ks] = zz; continue; }
        int c128 = ks * 32 + quad * 8;
        if constexpr (sizeof(TA) == 2) {
            const TA* Ah = (c128 < 64) ? A0 : A1;
            a[ks] = *(const half8*)((const _Float16*)Ah + (size_t)row * 64 + (c128 & 63));
        } else {
            const float* Ap = (const float*)A0 + (size_t)row * 128 + c128;
            float4 f0 = *(const float4*)Ap;
            float4 f1 = *(const float4*)(Ap + 4);
            half8 v;
            v[0] = (_Float16)f0.x; v[1] = (_Float16)f0.y; v[2] = (_Float16)f0.z; v[3] = (_Float16)f0.w;
            v[4] = (_Float16)f1.x; v[5] = (_Float16)f1.y; v[6] = (_Float16)f1.z; v[7] = (_Float16)f1.w;
            a[ks] = v;
        }
    }

    floatx4 acc[CT];
#pragma unroll
    for (int c = 0; c < CT; ++c) acc[c] = (floatx4){0.f, 0.f, 0.f, 0.f};

#pragma unroll
    for (int c = 0; c < CT; ++c) {
#pragma unroll
        for (int ks = 0; ks < 4; ++ks) {
            half8 b = Wf[(c * 4 + ks) * 64 + lane];
            acc[c] = __builtin_amdgcn_mfma_f32_16x16x32_f16(b, a[ks], acc[c], 0, 0, 0);
        }
    }

    if (ok) {
#pragma unroll
        for (int c = 0; c < CT; ++c) {
            __half* Ch = (NOUT == 64 || c < 4) ? C0 : C1;
            int coff = (NOUT == 64 || c < 4) ? c * 16 : (c - 4) * 16;
            __half2 h0 = __floats2half2_rn(acc[c][0], acc[c][1]);
            __half2 h1 = __floats2half2_rn(acc[c][2], acc[c][3]);
            uint2 u;
            __builtin_memcpy(&u.x, &h0, 4);
            __builtin_memcpy(&u.y, &h1, 4);
            *(uint2*)&Ch[(size_t)row * 64 + coff + quad * 4] = u;
        }
    }

    if (ATTN) {   // fused attn dots (fp32 from acc); reduce across quads
        float ps = 0.f, pd = 0.f;
#pragma unroll
        for (int c = 0; c < CT; ++c) {
#pragma unroll
            for (int reg = 0; reg < 4; ++reg) {
                float w = acc[c][reg];
                ps = fmaf(w, a_s[c * 16 + quad * 4 + reg], ps);
                pd = fmaf(w, a_d[c * 16 + quad * 4 + reg], pd);
            }
        }
        ps += __shfl_xor(ps, 16); ps += __shfl_xor(ps, 32);
        pd += __shfl_xor(pd, 16); pd += __shfl_xor(pd, 32);
        if (quad == 0 && ok) { asv[row] = ps; adv[row] = pd; }
    }
}

// fma 8 halves scaled by al into acc[0..7] (v_fma_mix-friendly form)
__device__ inline void fma_h8v(half8 h, float al, float* acc) {
#pragma unroll
    for (int k = 0; k < 8; ++k) acc[k] = fmaf(al, (float)h[k], acc[k]);
}

// ---------------- GAT aggregation: split tables, 2 compact passes ----------------

__global__ __launch_bounds__(256) void k_gat_agg(const __half* __restrict__ h0,
                                                 const __half* __restrict__ h1,
                                                 const int* __restrict__ cnt,
                                                 const u16* __restrict__ csr,
                                                 const float* __restrict__ asv,
                                                 const float* __restrict__ adv,
                                                 const float* __restrict__ bias,
                                                 __half* __restrict__ out0,
                                                 __half* __restrict__ out1) {
    __shared__ float alsL[4][88];
    __shared__ int   srcL[4][88];
    int lane = threadIdx.x & 63, wv = threadIdx.x >> 6;
    int d = blockIdx.x * 4 + wv;
    if (d >= NN) return;
    int deg = cnt[d]; if (deg > CAP) deg = CAP;
    const float advd = adv[d];
    const u16* rowp = csr + (size_t)d * CAP;

    // ---- phase A: exact softmax over <=80 edges in 2 register chunks ----
    int j0 = lane, j1 = lane + 64;
    int s0 = 0, s1 = 0;
    float e0 = -INFINITY, e1 = -INFINITY;
    if (j0 < deg) {
        s0 = rowp[j0];
        float t = asv[s0] + advd;
        e0 = (t >= 0.f) ? t : NEG * t;
    }
    if (j1 < deg) {
        s1 = rowp[j1];
        float t = asv[s1] + advd;
        e1 = (t >= 0.f) ? t : NEG * t;
    }
    float m = fmaxf(e0, e1);
#pragma unroll
    for (int off = 32; off; off >>= 1) m = fmaxf(m, __shfl_xor(m, off));
    float p0 = (j0 < deg) ? __expf(e0 - m) : 0.f;
    float p1 = (j1 < deg) ? __expf(e1 - m) : 0.f;
    float s = p0 + p1;
#pragma unroll
    for (int off = 32; off; off >>= 1) s += __shfl_xor(s, off);
    float inv = 1.f / s;
    alsL[wv][j0] = p0 * inv;
    srcL[wv][j0] = s0;
    if (j1 < 88) { alsL[wv][j1] = p1 * inv; srcL[wv][j1] = s1; }

    // ---- phase B: two compact passes, 8 edge-slots x 8 lanes x 8 cols ----
    int slot = lane >> 3, r = lane & 7;
    int degp = (deg + 7) & ~7;
#pragma unroll
    for (int half = 0; half < 2; ++half) {
        const __half* ht = half ? h1 : h0;
        __half* ot = half ? out1 : out0;
        float acc[8];
#pragma unroll
        for (int k = 0; k < 8; ++k) acc[k] = 0.f;

        for (int base = 0; base < degp; base += 8) {
            int idx = base + slot;
            float al = alsL[wv][idx];
            int   sj = srcL[wv][idx];
            half8 hv = *(const half8*)&ht[(size_t)sj * 64 + r * 8];
            fma_h8v(hv, al, acc);
        }
#pragma unroll
        for (int k = 0; k < 8; ++k) {
            acc[k] += __shfl_xor(acc[k], 8);
            acc[k] += __shfl_xor(acc[k], 16);
            acc[k] += __shfl_xor(acc[k], 32);
        }
        if (slot == 0) {
            __half2 ho[4];
#pragma unroll
            for (int k = 0; k < 4; ++k) {
                float oa = fmaxf(acc[2 * k]     + bias[half * 64 + r * 8 + 2 * k],     0.f);
                float ob = fmaxf(acc[2 * k + 1] + bias[half * 64 + r * 8 + 2 * k + 1], 0.f);
                ho[k] = __floats2half2_rn(oa, ob);
            }
            uint4 u;
            __builtin_memcpy(&u, &ho[0], 16);
            *(uint4*)&ot[(size_t)d * 64 + r * 8] = u;
        }
    }
}

// ---------------- GCN aggregation (64-col table already compact) ----------------

__global__ __launch_bounds__(256) void k_gcn_agg(const __half* __restrict__ h,
                                                 const int* __restrict__ cnt,
                                                 const u16* __restrict__ csr,
                                                 const float* __restrict__ bias,
                                                 __half* __restrict__ z) {
    __shared__ float nmL[4][88];
    __shared__ int   srcL[4][88];
    int lane = threadIdx.x & 63, wv = threadIdx.x >> 6;
    int d = blockIdx.x * 4 + wv;
    if (d >= NN) return;
    int degc = cnt[d];
    int deg = degc > CAP ? CAP : degc;
    float did = rsqrtf((float)degc);
    const u16* rowp = csr + (size_t)d * CAP;

    int j0 = lane, j1 = lane + 64;
    int s0 = 0, s1 = 0;
    float n0 = 0.f, n1 = 0.f;
    if (j0 < deg) { s0 = rowp[j0]; n0 = rsqrtf((float)cnt[s0]) * did; }
    if (j1 < deg) { s1 = rowp[j1]; n1 = rsqrtf((float)cnt[s1]) * did; }
    nmL[wv][j0] = n0;
    srcL[wv][j0] = s0;
    if (j1 < 88) { nmL[wv][j1] = n1; srcL[wv][j1] = s1; }

    int slot = lane >> 3, r = lane & 7;
    float acc[8];
#pragma unroll
    for (int k = 0; k < 8; ++k) acc[k] = 0.f;

    int degp = (deg + 7) & ~7;
    for (int base = 0; base < degp; base += 8) {
        int idx = base + slot;
        float nm = nmL[wv][idx];
        int   sj = srcL[wv][idx];
        half8 hv = *(const half8*)&h[(size_t)sj * 64 + r * 8];
        fma_h8v(hv, nm, acc);
    }
#pragma unroll
    for (int k = 0; k < 8; ++k) {
        acc[k] += __shfl_xor(acc[k], 8);
        acc[k] += __shfl_xor(acc[k], 16);
        acc[k] += __shfl_xor(acc[k], 32);
    }
    if (slot == 0) {
        __half2 ho[4];
#pragma unroll
        for (int k = 0; k < 4; ++k) {
            float oa = acc[2 * k]     + bias[r * 8 + 2 * k];
            float ob = acc[2 * k + 1] + bias[r * 8 + 2 * k + 1];
            ho[k] = __floats2half2_rn(oa, ob);
        }
        uint4 u;
        __builtin_memcpy(&u, &ho[0], 16);
        *(uint4*)&z[(size_t)d * 64 + r * 8] = u;
    }
}

// ---------------- link decode (fp16 z, fp32 dot) ----------------

__global__ __launch_bounds__(256) void k_decode(const __half* __restrict__ z,
                                                const int* __restrict__ eli,
                                                float* __restrict__ outp) {
    int lane = threadIdx.x & 63, wv = threadIdx.x >> 6;
    int g = lane >> 4, r = lane & 15;
    int idx = (blockIdx.x * 4 + wv) * 4 + g;
    if (idx >= NLBL) return;
    int a = eli[idx], b = eli[NLBL + idx];
    uint2 ua = *(const uint2*)&z[(size_t)a * 64 + r * 4];
    uint2 ub = *(const uint2*)&z[(size_t)b * 64 + r * 4];
    float2 a0 = __half22float2(*(__half2*)&ua.x);
    float2 a1 = __half22float2(*(__half2*)&ua.y);
    float2 b0 = __half22float2(*(__half2*)&ub.x);
    float2 b1 = __half22float2(*(__half2*)&ub.y);
    float v = a0.x * b0.x + a0.y * b0.y + a1.x * b1.x + a1.y * b1.y;
#pragma unroll
    for (int off = 8; off; off >>= 1) v += __shfl_xor(v, off);
    if (r == 0) outp[idx] = v;
}

// ---------------- launch ----------------

extern "C" void kernel_launch(void* const* d_in, const int* in_sizes, int n_in,
                              void* d_out, int out_size, void* d_ws, size_t ws_size,
                              hipStream_t stream) {
    const float* x   = (const float*)d_in[0];
    const int*   ei  = (const int*)d_in[1];
    const int*   eli = (const int*)d_in[2];
    const float* W1 = (const float*)d_in[3];
    const float* a1s = (const float*)d_in[4];
    const float* a1d = (const float*)d_in[5];
    const float* b1 = (const float*)d_in[6];
    const float* W2 = (const float*)d_in[7];
    const float* a2s = (const float*)d_in[8];
    const float* a2d = (const float*)d_in[9];
    const float* b2 = (const float*)d_in[10];
    const float* W3 = (const float*)d_in[11];
    const float* a3s = (const float*)d_in[12];
    const float* a3d = (const float*)d_in[13];
    const float* b3 = (const float*)d_in[14];
    const float* W4 = (const float*)d_in[15];
    const float* b4 = (const float*)d_in[16];
    float* outp = (float*)d_out;

    char* p = (char*)d_ws;
    auto alloc = [&](size_t bytes) -> char* {
        char* r = p;
        p += (bytes + 255) & ~(size_t)255;
        return r;
    };
    int*    cnt  = (int*)alloc((size_t)NN * 4);
    u16*    csr  = (u16*)alloc((size_t)NN * CAP * 2);
    int*    gcnt = (int*)alloc((size_t)NBK * 4);
    float*  asv  = (float*)alloc((size_t)NN * 4);
    float*  advv = (float*)alloc((size_t)NN * 4);
    __half* G0   = (__half*)alloc((size_t)NN * 64 * 2);    // gather table halves
    __half* G1   = (__half*)alloc((size_t)NN * 64 * 2);
    __half* B1a  = (__half*)alloc((size_t)NN * 64 * 2);    // layer outputs (split)
    __half* B1b  = (__half*)alloc((size_t)NN * 64 * 2);
    __half* B2a  = (__half*)alloc((size_t)NN * 64 * 2);
    __half* B2b  = (__half*)alloc((size_t)NN * 64 * 2);
    __half* zf   = (__half*)alloc((size_t)NN * 64 * 2);    // gcn output
    half8*  Wf1  = (half8*)alloc(2048 * 16);
    half8*  Wf2  = (half8*)alloc(2048 * 16);
    half8*  Wf3  = (half8*)alloc(2048 * 16);
    half8*  Wf4  = (half8*)alloc(1024 * 16);
    unsigned* bins = (unsigned*)alloc((size_t)NBK * CAPB * 4);

    const int gBin  = (NE + CHK - 1) / CHK;
    const int gGemm = (NN + 63) / 64;
    const int gNode = (NN + 3) / 4;
    const int gDec  = (NLBL + 15) / 16;

    k_prep_w<<<29, 256, 0, stream>>>(W1, W2, W3, W4, Wf1, Wf2, Wf3, Wf4, gcnt);
    k_bin<<<gBin, 256, 0, stream>>>(ei, gcnt, bins);
    k_build<<<NBK, 256, 0, stream>>>(bins, gcnt, cnt, csr);

    gemm_mfma<128, true, float><<<gGemm, 256, 0, stream>>>(x, x, Wf1, G0, G1, a1s, a1d, asv, advv, NN);
    k_gat_agg<<<gNode, 256, 0, stream>>>(G0, G1, cnt, csr, asv, advv, b1, B1a, B1b);

    gemm_mfma<128, true, __half><<<gGemm, 256, 0, stream>>>(B1a, B1b, Wf2, G0, G1, a2s, a2d, asv, advv, NN);
    k_gat_agg<<<gNode, 256, 0, stream>>>(G0, G1, cnt, csr, asv, advv, b2, B2a, B2b);

    gemm_mfma<128, true, __half><<<gGemm, 256, 0, stream>>>(B2a, B2b, Wf3, G0, G1, a3s, a3d, asv, advv, NN);
    k_gat_agg<<<gNode, 256, 0, stream>>>(G0, G1, cnt, csr, asv, advv, b3, B1a, B1b);

    gemm_mfma<64, false, __half><<<gGemm, 256, 0, stream>>>(B1a, B1b, Wf4, G0, G0, nullptr, nullptr, nullptr, nullptr, NN);
    k_gcn_agg<<<gNode, 256, 0, stream>>>(G0, cnt, csr, b4, zf);

    k_decode<<<gDec, 256, 0, stream>>>(zf, eli, outp);
}